// Round 2
// baseline (1553.827 us; speedup 1.0000x reference)
//
#include <hip/hip_runtime.h>
#include <hip/hip_bf16.h>

#define NN 100000
#define EE 1600000
#define DH 128
#define DOUT 40
#define BN_EPS 1e-5f

// ---------------- utility ----------------
__global__ void k_zero(int* __restrict__ p, int n) {
  int i = blockIdx.x * blockDim.x + threadIdx.x;
  if (i < n) p[i] = 0;
}

// ---------------- CSR build ----------------
__global__ void k_degree(const int* __restrict__ col, int* __restrict__ deg) {
  int e = blockIdx.x * blockDim.x + threadIdx.x;
  if (e < EE) atomicAdd(&deg[col[e]], 1);
}

__global__ void k_dinv(const int* __restrict__ deg, float* __restrict__ dinv) {
  int i = blockIdx.x * blockDim.x + threadIdx.x;
  if (i < NN) dinv[i] = (deg[i] > 0) ? rsqrtf((float)deg[i]) : 0.f;
}

__global__ void k_scan1(const int* __restrict__ deg, int* __restrict__ rowptr,
                        int* __restrict__ bsums, int n) {
  __shared__ int sm[1024];
  int i = blockIdx.x * 1024 + threadIdx.x;
  int v = (i < n) ? deg[i] : 0;
  sm[threadIdx.x] = v;
  __syncthreads();
  for (int off = 1; off < 1024; off <<= 1) {
    int t = (threadIdx.x >= off) ? sm[threadIdx.x - off] : 0;
    __syncthreads();
    sm[threadIdx.x] += t;
    __syncthreads();
  }
  if (i < n) rowptr[i + 1] = sm[threadIdx.x];
  if (threadIdx.x == 1023) bsums[blockIdx.x] = sm[1023];
}

__global__ void k_scan2(const int* __restrict__ bsums, int* __restrict__ boffs, int nb) {
  if (threadIdx.x == 0 && blockIdx.x == 0) {
    int run = 0;
    for (int b = 0; b < nb; ++b) { boffs[b] = run; run += bsums[b]; }
  }
}

__global__ void k_scan3(int* __restrict__ rowptr, const int* __restrict__ boffs, int n) {
  int i = blockIdx.x * blockDim.x + threadIdx.x;
  if (i == 0) rowptr[0] = 0;
  if (i < n) rowptr[i + 1] += boffs[i >> 10];
}

__global__ void k_scatter(const int* __restrict__ row, const int* __restrict__ col,
                          const int* __restrict__ rowptr, int* __restrict__ fill,
                          int* __restrict__ srcbuf) {
  int e = blockIdx.x * blockDim.x + threadIdx.x;
  if (e < EE) {
    int c = col[e];
    int p = atomicAdd(&fill[c], 1);
    srcbuf[rowptr[c] + p] = row[e];
  }
}

// ---------------- SPMM (gather): agg[c] = dinv[c] * sum_{src in N(c)} dinv[src]*h[src] ----------------
__global__ __launch_bounds__(256) void k_spmm(const float* __restrict__ h, float* __restrict__ agg,
                                              const int* __restrict__ rowptr,
                                              const int* __restrict__ srcbuf,
                                              const float* __restrict__ dinv) {
  int gid = blockIdx.x * 256 + threadIdx.x;
  int node = gid >> 6;
  int lane = gid & 63;
  if (node >= NN) return;
  const float2* h2 = (const float2*)h;
  int e0 = rowptr[node], e1 = rowptr[node + 1];
  float ax = 0.f, ay = 0.f;
  for (int e = e0; e < e1; ++e) {
    int s = srcbuf[e];
    float w = dinv[s];
    float2 v = h2[(size_t)s * 64 + lane];
    ax += w * v.x;
    ay += w * v.y;
  }
  float dc = dinv[node];
  float2 o;
  o.x = ax * dc;
  o.y = ay * dc;
  ((float2*)agg)[(size_t)node * 64 + lane] = o;
}

// ---------------- GEMM: C[N,128] = A[N,128] @ W[128,128]^T + b  (all fp32) ----------------
// 64-row tile, K chunked by 64. In-place C==A safe: block reads only its own rows, writes after all reads.
__global__ __launch_bounds__(256) void k_gemm128(const float* __restrict__ A, const float* __restrict__ W,
                                                 const float* __restrict__ bias, float* __restrict__ C,
                                                 int n) {
  __shared__ float As[64][68];   // [k][r]
  __shared__ float Ws[64][132];  // [k][c]
  int tx = threadIdx.x, ty = threadIdx.y;
  int t = ty * 16 + tx;
  int r0 = blockIdx.x * 64;
  float acc[4][8];
#pragma unroll
  for (int i = 0; i < 4; ++i)
#pragma unroll
    for (int j = 0; j < 8; ++j) acc[i][j] = 0.f;

  for (int k0 = 0; k0 < 128; k0 += 64) {
#pragma unroll
    for (int i = 0; i < 16; ++i) {
      int flat = t + i * 256;
      int r = flat >> 6, k = flat & 63;
      int gr = r0 + r;
      As[k][r] = (gr < n) ? A[(size_t)gr * 128 + k0 + k] : 0.f;
    }
#pragma unroll
    for (int i = 0; i < 32; ++i) {
      int flat = t + i * 256;
      int c = flat >> 6, k = flat & 63;
      Ws[k][c] = W[(size_t)c * 128 + k0 + k];
    }
    __syncthreads();
#pragma unroll 8
    for (int k = 0; k < 64; ++k) {
      float a[4], b[8];
#pragma unroll
      for (int i = 0; i < 4; ++i) a[i] = As[k][ty * 4 + i];
#pragma unroll
      for (int j = 0; j < 8; ++j) b[j] = Ws[k][tx * 8 + j];
#pragma unroll
      for (int i = 0; i < 4; ++i)
#pragma unroll
        for (int j = 0; j < 8; ++j) acc[i][j] += a[i] * b[j];
    }
    __syncthreads();
  }
#pragma unroll
  for (int i = 0; i < 4; ++i) {
    int gr = r0 + ty * 4 + i;
    if (gr < n) {
#pragma unroll
      for (int j = 0; j < 8; ++j) {
        int c = tx * 8 + j;
        C[(size_t)gr * 128 + c] = acc[i][j] + bias[c];
      }
    }
  }
}

// ---------------- BN stats / finalize / apply ----------------
__global__ void k_bnstats(const float* __restrict__ y, float* __restrict__ sums) {
  int j = threadIdx.x;  // 0..127
  float s = 0.f, s2 = 0.f;
  for (int r = blockIdx.x; r < NN; r += gridDim.x) {
    float v = y[(size_t)r * 128 + j];
    s += v;
    s2 += v * v;
  }
  atomicAdd(&sums[j], s);
  atomicAdd(&sums[128 + j], s2);
}

__global__ void k_bnfin(const float* __restrict__ sums, const float* __restrict__ gamma,
                        const float* __restrict__ beta, float* __restrict__ ss) {
  int j = threadIdx.x;  // 128
  float mu = sums[j] * (1.f / NN);
  float var = sums[128 + j] * (1.f / NN) - mu * mu;
  float sc = gamma[j] * rsqrtf(var + BN_EPS);
  ss[j] = sc;
  ss[128 + j] = beta[j] - mu * sc;
}

// h = relu(scale*y + shift) [+ res]; optionally also write x0 = result
__global__ __launch_bounds__(256) void k_bnapply(const float4* __restrict__ y, float4* __restrict__ h,
                                                 float4* __restrict__ x0, const float4* __restrict__ res,
                                                 const float* __restrict__ ss) {
  int i = blockIdx.x * 256 + threadIdx.x;
  if (i >= NN * 32) return;
  int j = i & 31;
  const float4* ss4 = (const float4*)ss;
  float4 sc = ss4[j];
  float4 sh = ss4[32 + j];
  float4 v = y[i];
  float4 o;
  o.x = fmaxf(fmaf(sc.x, v.x, sh.x), 0.f);
  o.y = fmaxf(fmaf(sc.y, v.y, sh.y), 0.f);
  o.z = fmaxf(fmaf(sc.z, v.z, sh.z), 0.f);
  o.w = fmaxf(fmaf(sc.w, v.w, sh.w), 0.f);
  if (res) {
    float4 r = res[i];
    o.x += r.x; o.y += r.y; o.z += r.z; o.w += r.w;
  }
  h[i] = o;
  if (x0) x0[i] = o;
}

// ---------------- classifier: out[N,40] = h @ cls_w^T + cls_b ----------------
__global__ __launch_bounds__(256) void k_cls(const float* __restrict__ A, const float* __restrict__ W,
                                             const float* __restrict__ bias, float* __restrict__ C, int n) {
  __shared__ float As[128][68];  // [k][r], r<64
  __shared__ float Ws[128][48];  // [k][c], c<48 (pad 40..47 = 0)
  int tx = threadIdx.x, ty = threadIdx.y;
  int t = ty * 16 + tx;
  int r0 = blockIdx.x * 64;
#pragma unroll
  for (int i = 0; i < 32; ++i) {
    int flat = t + i * 256;
    int r = flat >> 7, k = flat & 127;
    int gr = r0 + r;
    As[k][r] = (gr < n) ? A[(size_t)gr * 128 + k] : 0.f;
  }
#pragma unroll
  for (int i = 0; i < 20; ++i) {
    int flat = t + i * 256;
    int c = flat >> 7, k = flat & 127;
    Ws[k][c] = W[flat];
  }
  for (int i = t; i < 128 * 8; i += 256) {
    int k = i >> 3, c = 40 + (i & 7);
    Ws[k][c] = 0.f;
  }
  __syncthreads();
  float acc[4][3];
#pragma unroll
  for (int i = 0; i < 4; ++i)
#pragma unroll
    for (int j = 0; j < 3; ++j) acc[i][j] = 0.f;
  int cb = tx * 3;
#pragma unroll 8
  for (int k = 0; k < 128; ++k) {
    float a[4], b[3];
#pragma unroll
    for (int i = 0; i < 4; ++i) a[i] = As[k][ty * 4 + i];
#pragma unroll
    for (int j = 0; j < 3; ++j) b[j] = Ws[k][cb + j];
#pragma unroll
    for (int i = 0; i < 4; ++i)
#pragma unroll
      for (int j = 0; j < 3; ++j) acc[i][j] += a[i] * b[j];
  }
#pragma unroll
  for (int i = 0; i < 4; ++i) {
    int gr = r0 + ty * 4 + i;
    if (gr < n) {
#pragma unroll
      for (int j = 0; j < 3; ++j) {
        int c = cb + j;
        if (c < DOUT)
          C[(size_t)gr * DOUT + c] = acc[i][j] + bias[c];
      }
    }
  }
}

// ---------------- launch ----------------
extern "C" void kernel_launch(void* const* d_in, const int* in_sizes, int n_in,
                              void* d_out, int out_size, void* d_ws, size_t ws_size,
                              hipStream_t stream) {
  const float* x      = (const float*)d_in[0];
  const int*   ei     = (const int*)d_in[1];
  const float* fc_w   = (const float*)d_in[2];
  const float* fc_b   = (const float*)d_in[3];
  const float* conv_w = (const float*)d_in[4];
  const float* conv_b = (const float*)d_in[5];
  const float* bn_g   = (const float*)d_in[6];
  const float* bn_b   = (const float*)d_in[7];
  const float* cls_w  = (const float*)d_in[8];
  const float* cls_b  = (const float*)d_in[9];
  const int* row  = ei;       // edge_index[0]
  const int* colv = ei + EE;  // edge_index[1]

  char* w = (char*)d_ws;
  auto alloc = [&](size_t bytes) {
    char* p = w;
    w += (bytes + 255) & ~(size_t)255;
    return p;
  };
  float* s      = (float*)alloc((size_t)NN * 128 * 4);
  float* h      = (float*)alloc((size_t)NN * 128 * 4);
  float* x0     = (float*)alloc((size_t)NN * 128 * 4);
  int*   srcbuf = (int*)alloc((size_t)EE * 4);
  int*   rowptr = (int*)alloc((size_t)(NN + 1) * 4);
  int*   bsums  = (int*)alloc(1024);
  int*   boffs  = (int*)alloc(1024);
  float* dinv   = (float*)alloc((size_t)NN * 4);
  // contiguous zero region: deg | fill | sums(4 layers x 256 floats)
  int*   deg    = (int*)alloc((size_t)NN * 4 + (size_t)NN * 4 + 8 * 128 * 4);
  int*   fill   = deg + NN;
  float* sums   = (float*)(fill + NN);
  float* ss     = (float*)alloc(8 * 128 * 4);  // scale/shift x 4 layers

  const int zwords = NN + NN + 8 * 128;
  k_zero<<<(zwords + 255) / 256, 256, 0, stream>>>(deg, zwords);
  k_degree<<<(EE + 255) / 256, 256, 0, stream>>>(colv, deg);
  k_dinv<<<(NN + 255) / 256, 256, 0, stream>>>(deg, dinv);
  k_scan1<<<(NN + 1023) / 1024, 1024, 0, stream>>>(deg, rowptr, bsums, NN);
  k_scan2<<<1, 64, 0, stream>>>(bsums, boffs, (NN + 1023) / 1024);
  k_scan3<<<(NN + 255) / 256, 256, 0, stream>>>(rowptr, boffs, NN);
  k_scatter<<<(EE + 255) / 256, 256, 0, stream>>>(row, colv, rowptr, fill, srcbuf);

  dim3 b16(16, 16);
  int gblocks = (NN + 63) / 64;

  // layer 0: fc + BN + relu, save x0
  k_gemm128<<<gblocks, b16, 0, stream>>>(x, fc_w, fc_b, s, NN);
  k_bnstats<<<512, 128, 0, stream>>>(s, sums + 0 * 256);
  k_bnfin<<<1, 128, 0, stream>>>(sums + 0 * 256, bn_g + 0 * 128, bn_b + 0 * 128, ss + 0 * 256);
  k_bnapply<<<(NN * 32 + 255) / 256, 256, 0, stream>>>((const float4*)s, (float4*)h, (float4*)x0,
                                                       nullptr, ss + 0 * 256);
  // conv layers
  for (int i = 0; i < 3; ++i) {
    k_spmm<<<(NN * 64 + 255) / 256, 256, 0, stream>>>(h, s, rowptr, srcbuf, dinv);
    k_gemm128<<<gblocks, b16, 0, stream>>>(s, conv_w + (size_t)i * 128 * 128,
                                           conv_b + (size_t)i * 128, s, NN);
    k_bnstats<<<512, 128, 0, stream>>>(s, sums + (size_t)(i + 1) * 256);
    k_bnfin<<<1, 128, 0, stream>>>(sums + (size_t)(i + 1) * 256, bn_g + (size_t)(i + 1) * 128,
                                   bn_b + (size_t)(i + 1) * 128, ss + (size_t)(i + 1) * 256);
    k_bnapply<<<(NN * 32 + 255) / 256, 256, 0, stream>>>((const float4*)s, (float4*)h, nullptr,
                                                         (const float4*)x0, ss + (size_t)(i + 1) * 256);
  }
  // classifier
  k_cls<<<gblocks, b16, 0, stream>>>(h, cls_w, cls_b, (float*)d_out, NN);
}

// Round 3
// 1039.398 us; speedup vs baseline: 1.4949x; 1.4949x over previous
//
#include <hip/hip_runtime.h>
#include <hip/hip_bf16.h>

#define NN 100000
#define EE 1600000
#define DH 128
#define DOUT 40
#define BN_EPS 1e-5f

typedef unsigned int uint;
typedef unsigned short ushort;
typedef __attribute__((ext_vector_type(8))) short bf16x8;
typedef __attribute__((ext_vector_type(4))) float f32x4;

__device__ __forceinline__ float b2f(uint u) { return __uint_as_float(u << 16); }
__device__ __forceinline__ ushort f2b(float f) {
  __hip_bfloat16 b = __float2bfloat16(f);
  return *reinterpret_cast<ushort*>(&b);
}

// ---------------- utility ----------------
__global__ void k_zero(int* __restrict__ p, int n) {
  int i = blockIdx.x * blockDim.x + threadIdx.x;
  if (i < n) p[i] = 0;
}

// fp32 -> bf16 cast, 4 elems/thread
__global__ void k_cast(const float4* __restrict__ src, uint2* __restrict__ dst, int n4) {
  int i = blockIdx.x * blockDim.x + threadIdx.x;
  if (i < n4) {
    float4 v = src[i];
    uint2 o;
    o.x = (uint)f2b(v.x) | ((uint)f2b(v.y) << 16);
    o.y = (uint)f2b(v.z) | ((uint)f2b(v.w) << 16);
    dst[i] = o;
  }
}

// ---------------- CSR build ----------------
__global__ void k_degree(const int* __restrict__ col, int* __restrict__ deg) {
  int e = blockIdx.x * blockDim.x + threadIdx.x;
  if (e < EE) atomicAdd(&deg[col[e]], 1);
}

__global__ void k_dinv(const int* __restrict__ deg, float* __restrict__ dinv) {
  int i = blockIdx.x * blockDim.x + threadIdx.x;
  if (i < NN) dinv[i] = (deg[i] > 0) ? rsqrtf((float)deg[i]) : 0.f;
}

__global__ void k_scan1(const int* __restrict__ deg, int* __restrict__ rowptr,
                        int* __restrict__ bsums, int n) {
  __shared__ int sm[1024];
  int i = blockIdx.x * 1024 + threadIdx.x;
  int v = (i < n) ? deg[i] : 0;
  sm[threadIdx.x] = v;
  __syncthreads();
  for (int off = 1; off < 1024; off <<= 1) {
    int t = (threadIdx.x >= off) ? sm[threadIdx.x - off] : 0;
    __syncthreads();
    sm[threadIdx.x] += t;
    __syncthreads();
  }
  if (i < n) rowptr[i + 1] = sm[threadIdx.x];
  if (threadIdx.x == 1023) bsums[blockIdx.x] = sm[1023];
}

__global__ void k_scan2(const int* __restrict__ bsums, int* __restrict__ boffs, int nb) {
  if (threadIdx.x == 0 && blockIdx.x == 0) {
    int run = 0;
    for (int b = 0; b < nb; ++b) { boffs[b] = run; run += bsums[b]; }
  }
}

__global__ void k_scan3(int* __restrict__ rowptr, const int* __restrict__ boffs, int n) {
  int i = blockIdx.x * blockDim.x + threadIdx.x;
  if (i == 0) rowptr[0] = 0;
  if (i < n) rowptr[i + 1] += boffs[i >> 10];
}

__global__ void k_scatter(const int* __restrict__ row, const int* __restrict__ col,
                          const int* __restrict__ rowptr, int* __restrict__ fill,
                          int* __restrict__ srcbuf) {
  int e = blockIdx.x * blockDim.x + threadIdx.x;
  if (e < EE) {
    int c = col[e];
    int p = atomicAdd(&fill[c], 1);
    srcbuf[rowptr[c] + p] = row[e];
  }
}

// ---------------- SPMM (gather, bf16 h): agg[c] = dinv[c] * sum dinv[src]*h[src] ----------------
__global__ __launch_bounds__(256) void k_spmm(const uint* __restrict__ h, uint* __restrict__ agg,
                                              const int* __restrict__ rowptr,
                                              const int* __restrict__ srcbuf,
                                              const float* __restrict__ dinv) {
  int gid = blockIdx.x * 256 + threadIdx.x;
  int node = gid >> 6;
  int lane = gid & 63;
  if (node >= NN) return;
  int e0 = rowptr[node], e1 = rowptr[node + 1];
  float ax = 0.f, ay = 0.f;
  for (int e = e0; e < e1; ++e) {
    int s = srcbuf[e];
    float wgt = dinv[s];
    uint v = h[(size_t)s * 64 + lane];
    ax = fmaf(wgt, b2f(v & 0xffffu), ax);
    ay = fmaf(wgt, b2f(v >> 16), ay);
  }
  float dc = dinv[node];
  agg[(size_t)node * 64 + lane] = (uint)f2b(ax * dc) | ((uint)f2b(ay * dc) << 16);
}

// ---------------- MFMA GEMM: Y[N,128](bf16) = A[N,128](bf16) @ W^T(bf16) + bias(f32) ----------------
// Also accumulates per-column BN stats (sum, sumsq) of pre-relu Y into sums[0..127], sums[128..255].
__global__ __launch_bounds__(256) void k_mgemm(const ushort* __restrict__ A,
                                               const ushort* __restrict__ W,
                                               const float* __restrict__ bias,
                                               ushort* __restrict__ Y,
                                               float* __restrict__ sums, int n) {
  __shared__ ushort As[64][136];   // +8 pad: b128 reads land 2-way (free)
  __shared__ ushort Ws[128][136];
  __shared__ float ls1[4][128];
  __shared__ float ls2[4][128];
  int t = threadIdx.x;
  int w = t >> 6, l = t & 63;
  int quad = l >> 4, m = l & 15;
  int r0 = blockIdx.x * 64;
  // stage A tile (64x128 bf16)
#pragma unroll
  for (int i = 0; i < 4; ++i) {
    int flat = (t + i * 256) * 8;
    int r = flat >> 7, k = flat & 127;
    uint4 v = make_uint4(0, 0, 0, 0);
    if (r0 + r < n) v = *(const uint4*)&A[(size_t)(r0 + r) * 128 + k];
    *(uint4*)&As[r][k] = v;
  }
  // stage W (128x128 bf16)
#pragma unroll
  for (int i = 0; i < 8; ++i) {
    int flat = (t + i * 256) * 8;
    int r = flat >> 7, k = flat & 127;
    *(uint4*)&Ws[r][k] = *(const uint4*)&W[flat];
  }
  __syncthreads();
  // A fragments: A[m=lane&15][k=quad*8+j]
  bf16x8 af[4];
#pragma unroll
  for (int ks = 0; ks < 4; ++ks)
    af[ks] = *(const bf16x8*)&As[w * 16 + m][ks * 32 + quad * 8];
#pragma unroll
  for (int ct = 0; ct < 8; ++ct) {
    f32x4 acc = {0.f, 0.f, 0.f, 0.f};
#pragma unroll
    for (int ks = 0; ks < 4; ++ks) {
      bf16x8 bf = *(const bf16x8*)&Ws[ct * 16 + m][ks * 32 + quad * 8];
      acc = __builtin_amdgcn_mfma_f32_16x16x32_bf16(af[ks], bf, acc, 0, 0, 0);
    }
    int c = ct * 16 + m;  // C/D layout: col = lane&15, row = quad*4 + reg
    float b = bias[c];
    float s1 = 0.f, s2 = 0.f;
    int rbase = r0 + w * 16 + quad * 4;
#pragma unroll
    for (int i = 0; i < 4; ++i) {
      int r = rbase + i;
      if (r < n) {
        float v = acc[i] + b;
        s1 += v;
        s2 += v * v;
        Y[(size_t)r * 128 + c] = f2b(v);
      }
    }
    s1 += __shfl_xor(s1, 16);
    s1 += __shfl_xor(s1, 32);
    s2 += __shfl_xor(s2, 16);
    s2 += __shfl_xor(s2, 32);
    if (quad == 0) {
      ls1[w][c] = s1;
      ls2[w][c] = s2;
    }
  }
  __syncthreads();
  if (t < 128) {
    float a1 = ls1[0][t] + ls1[1][t] + ls1[2][t] + ls1[3][t];
    float a2 = ls2[0][t] + ls2[1][t] + ls2[2][t] + ls2[3][t];
    atomicAdd(&sums[t], a1);
    atomicAdd(&sums[128 + t], a2);
  }
}

// ---------------- BN finalize ----------------
__global__ void k_bnfin(const float* __restrict__ sums, const float* __restrict__ gamma,
                        const float* __restrict__ beta, float* __restrict__ ss) {
  int j = threadIdx.x;  // 128
  float mu = sums[j] * (1.f / NN);
  float var = sums[128 + j] * (1.f / NN) - mu * mu;
  float sc = gamma[j] * rsqrtf(var + BN_EPS);
  ss[j] = sc;
  ss[128 + j] = beta[j] - mu * sc;
}

// h = relu(scale*y + shift) [+ res]; all activations bf16; optionally duplicate into x0
__global__ __launch_bounds__(256) void k_bnapply(const uint2* __restrict__ y, uint2* __restrict__ h,
                                                 uint2* __restrict__ x0, const uint2* __restrict__ res,
                                                 const float* __restrict__ ss) {
  int i = blockIdx.x * 256 + threadIdx.x;
  if (i >= NN * 32) return;
  int j = i & 31;
  float4 sc = ((const float4*)ss)[j];
  float4 sh = ((const float4*)ss)[32 + j];
  uint2 u = y[i];
  float v0 = b2f(u.x & 0xffffu), v1 = b2f(u.x >> 16);
  float v2 = b2f(u.y & 0xffffu), v3 = b2f(u.y >> 16);
  float o0 = fmaxf(fmaf(sc.x, v0, sh.x), 0.f);
  float o1 = fmaxf(fmaf(sc.y, v1, sh.y), 0.f);
  float o2 = fmaxf(fmaf(sc.z, v2, sh.z), 0.f);
  float o3 = fmaxf(fmaf(sc.w, v3, sh.w), 0.f);
  if (res) {
    uint2 r = res[i];
    o0 += b2f(r.x & 0xffffu);
    o1 += b2f(r.x >> 16);
    o2 += b2f(r.y & 0xffffu);
    o3 += b2f(r.y >> 16);
  }
  uint2 o;
  o.x = (uint)f2b(o0) | ((uint)f2b(o1) << 16);
  o.y = (uint)f2b(o2) | ((uint)f2b(o3) << 16);
  h[i] = o;
  if (x0) x0[i] = o;
}

// ---------------- classifier MFMA: out[N,40](f32) = h(bf16) @ cls_w^T(bf16) + cls_b ----------------
__global__ __launch_bounds__(256) void k_mcls(const ushort* __restrict__ A,
                                              const ushort* __restrict__ W,
                                              const float* __restrict__ bias,
                                              float* __restrict__ out, int n) {
  __shared__ ushort As[64][136];
  __shared__ ushort Ws[48][136];  // rows 40..47 zero
  int t = threadIdx.x;
  int w = t >> 6, l = t & 63;
  int quad = l >> 4, m = l & 15;
  int r0 = blockIdx.x * 64;
#pragma unroll
  for (int i = 0; i < 4; ++i) {
    int flat = (t + i * 256) * 8;
    int r = flat >> 7, k = flat & 127;
    uint4 v = make_uint4(0, 0, 0, 0);
    if (r0 + r < n) v = *(const uint4*)&A[(size_t)(r0 + r) * 128 + k];
    *(uint4*)&As[r][k] = v;
  }
#pragma unroll
  for (int i = 0; i < 3; ++i) {
    int slot = t + i * 256;  // < 768 = 48*128/8
    int flat = slot * 8;
    int r = flat >> 7, k = flat & 127;
    uint4 v = make_uint4(0, 0, 0, 0);
    if (r < 40) v = *(const uint4*)&W[flat];
    *(uint4*)&Ws[r][k] = v;
  }
  __syncthreads();
  bf16x8 af[4];
#pragma unroll
  for (int ks = 0; ks < 4; ++ks)
    af[ks] = *(const bf16x8*)&As[w * 16 + m][ks * 32 + quad * 8];
#pragma unroll
  for (int ct = 0; ct < 3; ++ct) {
    f32x4 acc = {0.f, 0.f, 0.f, 0.f};
#pragma unroll
    for (int ks = 0; ks < 4; ++ks) {
      bf16x8 bf = *(const bf16x8*)&Ws[ct * 16 + m][ks * 32 + quad * 8];
      acc = __builtin_amdgcn_mfma_f32_16x16x32_bf16(af[ks], bf, acc, 0, 0, 0);
    }
    int c = ct * 16 + m;
    if (c < DOUT) {
      float b = bias[c];
      int rbase = r0 + w * 16 + quad * 4;
#pragma unroll
      for (int i = 0; i < 4; ++i) {
        int r = rbase + i;
        if (r < n) out[(size_t)r * DOUT + c] = acc[i] + b;
      }
    }
  }
}

// ---------------- launch ----------------
extern "C" void kernel_launch(void* const* d_in, const int* in_sizes, int n_in,
                              void* d_out, int out_size, void* d_ws, size_t ws_size,
                              hipStream_t stream) {
  const float* x      = (const float*)d_in[0];
  const int*   ei     = (const int*)d_in[1];
  const float* fc_w   = (const float*)d_in[2];
  const float* fc_b   = (const float*)d_in[3];
  const float* conv_w = (const float*)d_in[4];
  const float* conv_b = (const float*)d_in[5];
  const float* bn_g   = (const float*)d_in[6];
  const float* bn_b   = (const float*)d_in[7];
  const float* cls_w  = (const float*)d_in[8];
  const float* cls_b  = (const float*)d_in[9];
  const int* row  = ei;       // edge_index[0]
  const int* colv = ei + EE;  // edge_index[1]

  char* w = (char*)d_ws;
  auto alloc = [&](size_t bytes) {
    char* p = w;
    w += (bytes + 255) & ~(size_t)255;
    return p;
  };
  ushort* xb     = (ushort*)alloc((size_t)NN * 128 * 2);
  ushort* hb     = (ushort*)alloc((size_t)NN * 128 * 2);
  ushort* x0b    = (ushort*)alloc((size_t)NN * 128 * 2);
  ushort* aggb   = (ushort*)alloc((size_t)NN * 128 * 2);
  ushort* yb     = (ushort*)alloc((size_t)NN * 128 * 2);
  ushort* wb_fc  = (ushort*)alloc(128 * 128 * 2);
  ushort* wb_cv  = (ushort*)alloc(3 * 128 * 128 * 2);
  ushort* wb_cls = (ushort*)alloc(DOUT * 128 * 2);
  int*   srcbuf = (int*)alloc((size_t)EE * 4);
  int*   rowptr = (int*)alloc((size_t)(NN + 1) * 4);
  int*   bsums  = (int*)alloc(1024);
  int*   boffs  = (int*)alloc(1024);
  float* dinv   = (float*)alloc((size_t)NN * 4);
  // contiguous zero region: deg | fill | sums(4 layers x 256 floats)
  int*   deg    = (int*)alloc((size_t)NN * 4 + (size_t)NN * 4 + 1024 * 4);
  int*   fill   = deg + NN;
  float* sums   = (float*)(fill + NN);
  float* ss     = (float*)alloc(1024 * 4);  // scale/shift x 4 layers

  // casts
  k_cast<<<(NN * 128 / 4 + 255) / 256, 256, 0, stream>>>((const float4*)x, (uint2*)xb, NN * 128 / 4);
  k_cast<<<(128 * 128 / 4 + 255) / 256, 256, 0, stream>>>((const float4*)fc_w, (uint2*)wb_fc, 128 * 128 / 4);
  k_cast<<<(3 * 128 * 128 / 4 + 255) / 256, 256, 0, stream>>>((const float4*)conv_w, (uint2*)wb_cv, 3 * 128 * 128 / 4);
  k_cast<<<(DOUT * 128 / 4 + 255) / 256, 256, 0, stream>>>((const float4*)cls_w, (uint2*)wb_cls, DOUT * 128 / 4);

  // CSR build
  const int zwords = NN + NN + 1024;
  k_zero<<<(zwords + 255) / 256, 256, 0, stream>>>(deg, zwords);
  k_degree<<<(EE + 255) / 256, 256, 0, stream>>>(colv, deg);
  k_dinv<<<(NN + 255) / 256, 256, 0, stream>>>(deg, dinv);
  k_scan1<<<(NN + 1023) / 1024, 1024, 0, stream>>>(deg, rowptr, bsums, NN);
  k_scan2<<<1, 64, 0, stream>>>(bsums, boffs, (NN + 1023) / 1024);
  k_scan3<<<(NN + 255) / 256, 256, 0, stream>>>(rowptr, boffs, NN);
  k_scatter<<<(EE + 255) / 256, 256, 0, stream>>>(row, colv, rowptr, fill, srcbuf);

  int gblocks = (NN + 63) / 64;
  int ablocks = (NN * 32 + 255) / 256;

  // layer 0: fc + BN + relu, save x0
  k_mgemm<<<gblocks, 256, 0, stream>>>(xb, wb_fc, fc_b, yb, sums + 0 * 256, NN);
  k_bnfin<<<1, 128, 0, stream>>>(sums + 0 * 256, bn_g + 0 * 128, bn_b + 0 * 128, ss + 0 * 256);
  k_bnapply<<<ablocks, 256, 0, stream>>>((const uint2*)yb, (uint2*)hb, (uint2*)x0b, nullptr, ss + 0 * 256);
  // conv layers
  for (int i = 0; i < 3; ++i) {
    k_spmm<<<(NN * 64 + 255) / 256, 256, 0, stream>>>((const uint*)hb, (uint*)aggb, rowptr, srcbuf, dinv);
    k_mgemm<<<gblocks, 256, 0, stream>>>(aggb, wb_cv + (size_t)i * 128 * 128, conv_b + (size_t)i * 128,
                                         yb, sums + (size_t)(i + 1) * 256, NN);
    k_bnfin<<<1, 128, 0, stream>>>(sums + (size_t)(i + 1) * 256, bn_g + (size_t)(i + 1) * 128,
                                   bn_b + (size_t)(i + 1) * 128, ss + (size_t)(i + 1) * 256);
    k_bnapply<<<ablocks, 256, 0, stream>>>((const uint2*)yb, (uint2*)hb, nullptr, (const uint2*)x0b,
                                           ss + (size_t)(i + 1) * 256);
  }
  // classifier
  k_mcls<<<gblocks, 256, 0, stream>>>(hb, wb_cls, cls_b, (float*)d_out, NN);
}

// Round 4
// 779.121 us; speedup vs baseline: 1.9943x; 1.3341x over previous
//
#include <hip/hip_runtime.h>
#include <hip/hip_bf16.h>

#define NN 100000
#define EE 1600000
#define DH 128
#define DOUT 40
#define BN_EPS 1e-5f

typedef unsigned int uint;
typedef unsigned short ushort;
typedef __attribute__((ext_vector_type(8))) short bf16x8;
typedef __attribute__((ext_vector_type(4))) float f32x4;

__device__ __forceinline__ float b2f(uint u) { return __uint_as_float(u << 16); }
__device__ __forceinline__ ushort f2b(float f) {
  __hip_bfloat16 b = __float2bfloat16(f);
  return *reinterpret_cast<ushort*>(&b);
}

// ---------------- utility ----------------
__global__ void k_zero(int* __restrict__ p, int n) {
  int i = blockIdx.x * blockDim.x + threadIdx.x;
  if (i < n) p[i] = 0;
}

// fp32 -> bf16 cast, 4 elems/thread
__global__ void k_cast(const float4* __restrict__ src, uint2* __restrict__ dst, int n4) {
  int i = blockIdx.x * blockDim.x + threadIdx.x;
  if (i < n4) {
    float4 v = src[i];
    uint2 o;
    o.x = (uint)f2b(v.x) | ((uint)f2b(v.y) << 16);
    o.y = (uint)f2b(v.z) | ((uint)f2b(v.w) << 16);
    dst[i] = o;
  }
}

// ---------------- CSR build ----------------
__global__ void k_degree(const int* __restrict__ col, int* __restrict__ deg) {
  int e = blockIdx.x * blockDim.x + threadIdx.x;
  if (e < EE) atomicAdd(&deg[col[e]], 1);
}

__global__ void k_dinv(const int* __restrict__ deg, float* __restrict__ dinv) {
  int i = blockIdx.x * blockDim.x + threadIdx.x;
  if (i < NN) dinv[i] = (deg[i] > 0) ? rsqrtf((float)deg[i]) : 0.f;
}

__global__ void k_scan1(const int* __restrict__ deg, int* __restrict__ rowptr,
                        int* __restrict__ bsums, int n) {
  __shared__ int sm[1024];
  int i = blockIdx.x * 1024 + threadIdx.x;
  int v = (i < n) ? deg[i] : 0;
  sm[threadIdx.x] = v;
  __syncthreads();
  for (int off = 1; off < 1024; off <<= 1) {
    int t = (threadIdx.x >= off) ? sm[threadIdx.x - off] : 0;
    __syncthreads();
    sm[threadIdx.x] += t;
    __syncthreads();
  }
  if (i < n) rowptr[i + 1] = sm[threadIdx.x];
  if (threadIdx.x == 1023) bsums[blockIdx.x] = sm[1023];
}

__global__ void k_scan2(const int* __restrict__ bsums, int* __restrict__ boffs, int nb) {
  if (threadIdx.x == 0 && blockIdx.x == 0) {
    int run = 0;
    for (int b = 0; b < nb; ++b) { boffs[b] = run; run += bsums[b]; }
  }
}

__global__ void k_scan3(int* __restrict__ rowptr, const int* __restrict__ boffs, int n) {
  int i = blockIdx.x * blockDim.x + threadIdx.x;
  if (i == 0) rowptr[0] = 0;
  if (i < n) rowptr[i + 1] += boffs[i >> 10];
}

__global__ void k_scatter(const int* __restrict__ row, const int* __restrict__ col,
                          const int* __restrict__ rowptr, int* __restrict__ fill,
                          int* __restrict__ srcbuf) {
  int e = blockIdx.x * blockDim.x + threadIdx.x;
  if (e < EE) {
    int c = col[e];
    int p = atomicAdd(&fill[c], 1);
    srcbuf[rowptr[c] + p] = row[e];
  }
}

// ---------------- SPMM (gather, bf16 h, 4 edges in flight per wave) ----------------
// agg[c] = dinv[c] * sum_{src in N(c)} dinv[src]*h[src]
// Wave = 1 node. 4 groups x 16 lanes; group g takes edges e0+g, e0+g+4, ...
// Each lane loads uint4 = 8 bf16 cols (16 lanes cover the 256B row).
// srcbuf is prefetched one iteration ahead to break the srcbuf->h chain.
__global__ __launch_bounds__(256) void k_spmm(const uint4* __restrict__ h4, uint4* __restrict__ agg4,
                                              const int* __restrict__ rowptr,
                                              const int* __restrict__ srcbuf,
                                              const float* __restrict__ dinv) {
  int gid = blockIdx.x * 256 + threadIdx.x;
  int node = gid >> 6;
  if (node >= NN) return;
  int lane = threadIdx.x & 63;
  int g = lane >> 4, li = lane & 15;
  int e0 = rowptr[node], e1 = rowptr[node + 1];
  float acc[8];
#pragma unroll
  for (int j = 0; j < 8; ++j) acc[j] = 0.f;

  int e = e0 + g;
  int s = (e < e1) ? srcbuf[e] : 0;  // prefetch
  while (e < e1) {
    int en = e + 4;
    int sn = (en < e1) ? srcbuf[en] : 0;  // prefetch next; current h-load doesn't wait on it
    float wgt = dinv[s];
    uint4 v = h4[(size_t)s * 16 + li];
    acc[0] = fmaf(wgt, b2f(v.x & 0xffffu), acc[0]);
    acc[1] = fmaf(wgt, b2f(v.x >> 16), acc[1]);
    acc[2] = fmaf(wgt, b2f(v.y & 0xffffu), acc[2]);
    acc[3] = fmaf(wgt, b2f(v.y >> 16), acc[3]);
    acc[4] = fmaf(wgt, b2f(v.z & 0xffffu), acc[4]);
    acc[5] = fmaf(wgt, b2f(v.z >> 16), acc[5]);
    acc[6] = fmaf(wgt, b2f(v.w & 0xffffu), acc[6]);
    acc[7] = fmaf(wgt, b2f(v.w >> 16), acc[7]);
    s = sn;
    e = en;
  }
#pragma unroll
  for (int j = 0; j < 8; ++j) {
    acc[j] += __shfl_xor(acc[j], 16);
    acc[j] += __shfl_xor(acc[j], 32);
  }
  if (g == 0) {
    float dc = dinv[node];
    uint4 o;
    o.x = (uint)f2b(acc[0] * dc) | ((uint)f2b(acc[1] * dc) << 16);
    o.y = (uint)f2b(acc[2] * dc) | ((uint)f2b(acc[3] * dc) << 16);
    o.z = (uint)f2b(acc[4] * dc) | ((uint)f2b(acc[5] * dc) << 16);
    o.w = (uint)f2b(acc[6] * dc) | ((uint)f2b(acc[7] * dc) << 16);
    agg4[(size_t)node * 16 + li] = o;
  }
}

// ---------------- MFMA GEMM: Y[N,128](bf16) = A[N,128](bf16) @ W^T(bf16) + bias(f32) ----------------
// Also accumulates per-column BN stats (sum, sumsq) of pre-relu Y into sums[0..127], sums[128..255].
__global__ __launch_bounds__(256) void k_mgemm(const ushort* __restrict__ A,
                                               const ushort* __restrict__ W,
                                               const float* __restrict__ bias,
                                               ushort* __restrict__ Y,
                                               float* __restrict__ sums, int n) {
  __shared__ ushort As[64][136];   // +8 pad: b128 reads land 2-way (free)
  __shared__ ushort Ws[128][136];
  __shared__ float ls1[4][128];
  __shared__ float ls2[4][128];
  int t = threadIdx.x;
  int w = t >> 6, l = t & 63;
  int quad = l >> 4, m = l & 15;
  int r0 = blockIdx.x * 64;
  // stage A tile (64x128 bf16)
#pragma unroll
  for (int i = 0; i < 4; ++i) {
    int flat = (t + i * 256) * 8;
    int r = flat >> 7, k = flat & 127;
    uint4 v = make_uint4(0, 0, 0, 0);
    if (r0 + r < n) v = *(const uint4*)&A[(size_t)(r0 + r) * 128 + k];
    *(uint4*)&As[r][k] = v;
  }
  // stage W (128x128 bf16)
#pragma unroll
  for (int i = 0; i < 8; ++i) {
    int flat = (t + i * 256) * 8;
    int r = flat >> 7, k = flat & 127;
    *(uint4*)&Ws[r][k] = *(const uint4*)&W[flat];
  }
  __syncthreads();
  // A fragments: A[m=lane&15][k=quad*8+j]
  bf16x8 af[4];
#pragma unroll
  for (int ks = 0; ks < 4; ++ks)
    af[ks] = *(const bf16x8*)&As[w * 16 + m][ks * 32 + quad * 8];
#pragma unroll
  for (int ct = 0; ct < 8; ++ct) {
    f32x4 acc = {0.f, 0.f, 0.f, 0.f};
#pragma unroll
    for (int ks = 0; ks < 4; ++ks) {
      bf16x8 bf = *(const bf16x8*)&Ws[ct * 16 + m][ks * 32 + quad * 8];
      acc = __builtin_amdgcn_mfma_f32_16x16x32_bf16(af[ks], bf, acc, 0, 0, 0);
    }
    int c = ct * 16 + m;  // C/D layout: col = lane&15, row = quad*4 + reg
    float b = bias[c];
    float s1 = 0.f, s2 = 0.f;
    int rbase = r0 + w * 16 + quad * 4;
#pragma unroll
    for (int i = 0; i < 4; ++i) {
      int r = rbase + i;
      if (r < n) {
        float v = acc[i] + b;
        s1 += v;
        s2 += v * v;
        Y[(size_t)r * 128 + c] = f2b(v);
      }
    }
    s1 += __shfl_xor(s1, 16);
    s1 += __shfl_xor(s1, 32);
    s2 += __shfl_xor(s2, 16);
    s2 += __shfl_xor(s2, 32);
    if (quad == 0) {
      ls1[w][c] = s1;
      ls2[w][c] = s2;
    }
  }
  __syncthreads();
  if (t < 128) {
    float a1 = ls1[0][t] + ls1[1][t] + ls1[2][t] + ls1[3][t];
    float a2 = ls2[0][t] + ls2[1][t] + ls2[2][t] + ls2[3][t];
    atomicAdd(&sums[t], a1);
    atomicAdd(&sums[128 + t], a2);
  }
}

// ---------------- BN finalize ----------------
__global__ void k_bnfin(const float* __restrict__ sums, const float* __restrict__ gamma,
                        const float* __restrict__ beta, float* __restrict__ ss) {
  int j = threadIdx.x;  // 128
  float mu = sums[j] * (1.f / NN);
  float var = sums[128 + j] * (1.f / NN) - mu * mu;
  float sc = gamma[j] * rsqrtf(var + BN_EPS);
  ss[j] = sc;
  ss[128 + j] = beta[j] - mu * sc;
}

// h = relu(scale*y + shift) [+ res]; all activations bf16; optionally duplicate into x0
__global__ __launch_bounds__(256) void k_bnapply(const uint2* __restrict__ y, uint2* __restrict__ h,
                                                 uint2* __restrict__ x0, const uint2* __restrict__ res,
                                                 const float* __restrict__ ss) {
  int i = blockIdx.x * 256 + threadIdx.x;
  if (i >= NN * 32) return;
  int j = i & 31;
  float4 sc = ((const float4*)ss)[j];
  float4 sh = ((const float4*)ss)[32 + j];
  uint2 u = y[i];
  float v0 = b2f(u.x & 0xffffu), v1 = b2f(u.x >> 16);
  float v2 = b2f(u.y & 0xffffu), v3 = b2f(u.y >> 16);
  float o0 = fmaxf(fmaf(sc.x, v0, sh.x), 0.f);
  float o1 = fmaxf(fmaf(sc.y, v1, sh.y), 0.f);
  float o2 = fmaxf(fmaf(sc.z, v2, sh.z), 0.f);
  float o3 = fmaxf(fmaf(sc.w, v3, sh.w), 0.f);
  if (res) {
    uint2 r = res[i];
    o0 += b2f(r.x & 0xffffu);
    o1 += b2f(r.x >> 16);
    o2 += b2f(r.y & 0xffffu);
    o3 += b2f(r.y >> 16);
  }
  uint2 o;
  o.x = (uint)f2b(o0) | ((uint)f2b(o1) << 16);
  o.y = (uint)f2b(o2) | ((uint)f2b(o3) << 16);
  h[i] = o;
  if (x0) x0[i] = o;
}

// ---------------- classifier MFMA: out[N,40](f32) = h(bf16) @ cls_w^T(bf16) + cls_b ----------------
__global__ __launch_bounds__(256) void k_mcls(const ushort* __restrict__ A,
                                              const ushort* __restrict__ W,
                                              const float* __restrict__ bias,
                                              float* __restrict__ out, int n) {
  __shared__ ushort As[64][136];
  __shared__ ushort Ws[48][136];  // rows 40..47 zero
  int t = threadIdx.x;
  int w = t >> 6, l = t & 63;
  int quad = l >> 4, m = l & 15;
  int r0 = blockIdx.x * 64;
#pragma unroll
  for (int i = 0; i < 4; ++i) {
    int flat = (t + i * 256) * 8;
    int r = flat >> 7, k = flat & 127;
    uint4 v = make_uint4(0, 0, 0, 0);
    if (r0 + r < n) v = *(const uint4*)&A[(size_t)(r0 + r) * 128 + k];
    *(uint4*)&As[r][k] = v;
  }
#pragma unroll
  for (int i = 0; i < 3; ++i) {
    int slot = t + i * 256;  // < 768 = 48*128/8
    int flat = slot * 8;
    int r = flat >> 7, k = flat & 127;
    uint4 v = make_uint4(0, 0, 0, 0);
    if (r < 40) v = *(const uint4*)&W[flat];
    *(uint4*)&Ws[r][k] = v;
  }
  __syncthreads();
  bf16x8 af[4];
#pragma unroll
  for (int ks = 0; ks < 4; ++ks)
    af[ks] = *(const bf16x8*)&As[w * 16 + m][ks * 32 + quad * 8];
#pragma unroll
  for (int ct = 0; ct < 3; ++ct) {
    f32x4 acc = {0.f, 0.f, 0.f, 0.f};
#pragma unroll
    for (int ks = 0; ks < 4; ++ks) {
      bf16x8 bf = *(const bf16x8*)&Ws[ct * 16 + m][ks * 32 + quad * 8];
      acc = __builtin_amdgcn_mfma_f32_16x16x32_bf16(af[ks], bf, acc, 0, 0, 0);
    }
    int c = ct * 16 + m;
    if (c < DOUT) {
      float b = bias[c];
      int rbase = r0 + w * 16 + quad * 4;
#pragma unroll
      for (int i = 0; i < 4; ++i) {
        int r = rbase + i;
        if (r < n) out[(size_t)r * DOUT + c] = acc[i] + b;
      }
    }
  }
}

// ---------------- launch ----------------
extern "C" void kernel_launch(void* const* d_in, const int* in_sizes, int n_in,
                              void* d_out, int out_size, void* d_ws, size_t ws_size,
                              hipStream_t stream) {
  const float* x      = (const float*)d_in[0];
  const int*   ei     = (const int*)d_in[1];
  const float* fc_w   = (const float*)d_in[2];
  const float* fc_b   = (const float*)d_in[3];
  const float* conv_w = (const float*)d_in[4];
  const float* conv_b = (const float*)d_in[5];
  const float* bn_g   = (const float*)d_in[6];
  const float* bn_b   = (const float*)d_in[7];
  const float* cls_w  = (const float*)d_in[8];
  const float* cls_b  = (const float*)d_in[9];
  const int* row  = ei;       // edge_index[0]
  const int* colv = ei + EE;  // edge_index[1]

  char* w = (char*)d_ws;
  auto alloc = [&](size_t bytes) {
    char* p = w;
    w += (bytes + 255) & ~(size_t)255;
    return p;
  };
  ushort* xb     = (ushort*)alloc((size_t)NN * 128 * 2);
  ushort* hb     = (ushort*)alloc((size_t)NN * 128 * 2);
  ushort* x0b    = (ushort*)alloc((size_t)NN * 128 * 2);
  ushort* aggb   = (ushort*)alloc((size_t)NN * 128 * 2);
  ushort* yb     = (ushort*)alloc((size_t)NN * 128 * 2);
  ushort* wb_fc  = (ushort*)alloc(128 * 128 * 2);
  ushort* wb_cv  = (ushort*)alloc(3 * 128 * 128 * 2);
  ushort* wb_cls = (ushort*)alloc(DOUT * 128 * 2);
  int*   srcbuf = (int*)alloc((size_t)EE * 4);
  int*   rowptr = (int*)alloc((size_t)(NN + 1) * 4);
  int*   bsums  = (int*)alloc(1024);
  int*   boffs  = (int*)alloc(1024);
  float* dinv   = (float*)alloc((size_t)NN * 4);
  // contiguous zero region: deg | fill | sums(4 layers x 256 floats)
  int*   deg    = (int*)alloc((size_t)NN * 4 + (size_t)NN * 4 + 1024 * 4);
  int*   fill   = deg + NN;
  float* sums   = (float*)(fill + NN);
  float* ss     = (float*)alloc(1024 * 4);  // scale/shift x 4 layers

  // casts
  k_cast<<<(NN * 128 / 4 + 255) / 256, 256, 0, stream>>>((const float4*)x, (uint2*)xb, NN * 128 / 4);
  k_cast<<<(128 * 128 / 4 + 255) / 256, 256, 0, stream>>>((const float4*)fc_w, (uint2*)wb_fc, 128 * 128 / 4);
  k_cast<<<(3 * 128 * 128 / 4 + 255) / 256, 256, 0, stream>>>((const float4*)conv_w, (uint2*)wb_cv, 3 * 128 * 128 / 4);
  k_cast<<<(DOUT * 128 / 4 + 255) / 256, 256, 0, stream>>>((const float4*)cls_w, (uint2*)wb_cls, DOUT * 128 / 4);

  // CSR build
  const int zwords = NN + NN + 1024;
  k_zero<<<(zwords + 255) / 256, 256, 0, stream>>>(deg, zwords);
  k_degree<<<(EE + 255) / 256, 256, 0, stream>>>(colv, deg);
  k_dinv<<<(NN + 255) / 256, 256, 0, stream>>>(deg, dinv);
  k_scan1<<<(NN + 1023) / 1024, 1024, 0, stream>>>(deg, rowptr, bsums, NN);
  k_scan2<<<1, 64, 0, stream>>>(bsums, boffs, (NN + 1023) / 1024);
  k_scan3<<<(NN + 255) / 256, 256, 0, stream>>>(rowptr, boffs, NN);
  k_scatter<<<(EE + 255) / 256, 256, 0, stream>>>(row, colv, rowptr, fill, srcbuf);

  int gblocks = (NN + 63) / 64;
  int ablocks = (NN * 32 + 255) / 256;

  // layer 0: fc + BN + relu, save x0
  k_mgemm<<<gblocks, 256, 0, stream>>>(xb, wb_fc, fc_b, yb, sums + 0 * 256, NN);
  k_bnfin<<<1, 128, 0, stream>>>(sums + 0 * 256, bn_g + 0 * 128, bn_b + 0 * 128, ss + 0 * 256);
  k_bnapply<<<ablocks, 256, 0, stream>>>((const uint2*)yb, (uint2*)hb, (uint2*)x0b, nullptr, ss + 0 * 256);
  // conv layers
  for (int i = 0; i < 3; ++i) {
    k_spmm<<<(NN * 64 + 255) / 256, 256, 0, stream>>>((const uint4*)hb, (uint4*)aggb, rowptr, srcbuf, dinv);
    k_mgemm<<<gblocks, 256, 0, stream>>>(aggb, wb_cv + (size_t)i * 128 * 128, conv_b + (size_t)i * 128,
                                         yb, sums + (size_t)(i + 1) * 256, NN);
    k_bnfin<<<1, 128, 0, stream>>>(sums + (size_t)(i + 1) * 256, bn_g + (size_t)(i + 1) * 128,
                                   bn_b + (size_t)(i + 1) * 128, ss + (size_t)(i + 1) * 256);
    k_bnapply<<<ablocks, 256, 0, stream>>>((const uint2*)yb, (uint2*)hb, nullptr, (const uint2*)x0b,
                                           ss + (size_t)(i + 1) * 256);
  }
  // classifier
  k_mcls<<<gblocks, 256, 0, stream>>>(hb, wb_cls, cls_b, (float*)d_out, NN);
}

// Round 5
// 673.857 us; speedup vs baseline: 2.3059x; 1.1562x over previous
//
#include <hip/hip_runtime.h>
#include <hip/hip_bf16.h>

#define NN 100000
#define EE 1600000
#define DH 128
#define DOUT 40
#define BN_EPS 1e-5f

typedef unsigned int uint;
typedef unsigned short ushort;
typedef __attribute__((ext_vector_type(8))) short bf16x8;
typedef __attribute__((ext_vector_type(4))) float f32x4;

__device__ __forceinline__ float b2f(uint u) { return __uint_as_float(u << 16); }
__device__ __forceinline__ ushort f2b(float f) {
  __hip_bfloat16 b = __float2bfloat16(f);
  return *reinterpret_cast<ushort*>(&b);
}
__device__ __forceinline__ uint2 cast4(float4 v) {
  uint2 o;
  o.x = (uint)f2b(v.x) | ((uint)f2b(v.y) << 16);
  o.y = (uint)f2b(v.z) | ((uint)f2b(v.w) << 16);
  return o;
}

// ---------------- fused front: all fp32->bf16 casts + zero region ----------------
#define N4X   3200000   // x: NN*128/4
#define N4FC  4096      // 128*128/4
#define N4CV  12288     // 3*128*128/4
#define N4CLS 1280      // 40*128/4
#define NZ2   100512    // (NN+NN+1024)/2 uint2 zeros
__global__ __launch_bounds__(256) void k_front(const float4* __restrict__ xs, uint2* __restrict__ xd,
                                               const float4* __restrict__ w1s, uint2* __restrict__ w1d,
                                               const float4* __restrict__ w2s, uint2* __restrict__ w2d,
                                               const float4* __restrict__ w3s, uint2* __restrict__ w3d,
                                               uint2* __restrict__ zp) {
  int i = blockIdx.x * 256 + threadIdx.x;
  if (i < N4X) { xd[i] = cast4(xs[i]); return; }
  i -= N4X;
  if (i < N4FC) { w1d[i] = cast4(w1s[i]); return; }
  i -= N4FC;
  if (i < N4CV) { w2d[i] = cast4(w2s[i]); return; }
  i -= N4CV;
  if (i < N4CLS) { w3d[i] = cast4(w3s[i]); return; }
  i -= N4CLS;
  if (i < NZ2) zp[i] = make_uint2(0, 0);
}

// ---------------- CSR build ----------------
__global__ void k_degree(const int* __restrict__ col, int* __restrict__ deg) {
  int e = blockIdx.x * blockDim.x + threadIdx.x;
  if (e < EE) atomicAdd(&deg[col[e]], 1);
}

// block-scan of degrees + dinv computation fused
__global__ void k_scan1d(const int* __restrict__ deg, int* __restrict__ rowptr,
                         int* __restrict__ bsums, float* __restrict__ dinv, int n) {
  __shared__ int sm[1024];
  int i = blockIdx.x * 1024 + threadIdx.x;
  int v = (i < n) ? deg[i] : 0;
  if (i < n) dinv[i] = (v > 0) ? rsqrtf((float)v) : 0.f;
  sm[threadIdx.x] = v;
  __syncthreads();
  for (int off = 1; off < 1024; off <<= 1) {
    int t = (threadIdx.x >= off) ? sm[threadIdx.x - off] : 0;
    __syncthreads();
    sm[threadIdx.x] += t;
    __syncthreads();
  }
  if (i < n) rowptr[i + 1] = sm[threadIdx.x];
  if (threadIdx.x == 1023) bsums[blockIdx.x] = sm[1023];
}

__global__ void k_scan2(const int* __restrict__ bsums, int* __restrict__ boffs, int nb) {
  if (threadIdx.x == 0 && blockIdx.x == 0) {
    int run = 0;
    for (int b = 0; b < nb; ++b) { boffs[b] = run; run += bsums[b]; }
  }
}

__global__ void k_scan3(int* __restrict__ rowptr, const int* __restrict__ boffs, int n) {
  int i = blockIdx.x * blockDim.x + threadIdx.x;
  if (i == 0) rowptr[0] = 0;
  if (i < n) rowptr[i + 1] += boffs[i >> 10];
}

// ---------------- BN scale/shift derivation (block prologue helper) ----------------
__device__ __forceinline__ void bn_prologue(float* ssl, const float* __restrict__ sums,
                                            const float* __restrict__ gamma,
                                            const float* __restrict__ beta) {
  int t = threadIdx.x;
  if (t < 128) {
    float mu = sums[t] * (1.f / NN);
    float var = sums[128 + t] * (1.f / NN) - mu * mu;
    float sc = gamma[t] * rsqrtf(var + BN_EPS);
    ssl[t] = sc;
    ssl[128 + t] = beta[t] - mu * sc;
  }
  __syncthreads();
}

__device__ __forceinline__ uint2 bn_elem(uint2 u, float4 sc, float4 sh) {
  float o0 = fmaxf(fmaf(sc.x, b2f(u.x & 0xffffu), sh.x), 0.f);
  float o1 = fmaxf(fmaf(sc.y, b2f(u.x >> 16), sh.y), 0.f);
  float o2 = fmaxf(fmaf(sc.z, b2f(u.y & 0xffffu), sh.z), 0.f);
  float o3 = fmaxf(fmaf(sc.w, b2f(u.y >> 16), sh.w), 0.f);
  uint2 o;
  o.x = (uint)f2b(o0) | ((uint)f2b(o1) << 16);
  o.y = (uint)f2b(o2) | ((uint)f2b(o3) << 16);
  return o;
}

__device__ __forceinline__ uint2 bn_elem_res(uint2 u, uint2 r, float4 sc, float4 sh) {
  float o0 = fmaxf(fmaf(sc.x, b2f(u.x & 0xffffu), sh.x), 0.f) + b2f(r.x & 0xffffu);
  float o1 = fmaxf(fmaf(sc.y, b2f(u.x >> 16), sh.y), 0.f) + b2f(r.x >> 16);
  float o2 = fmaxf(fmaf(sc.z, b2f(u.y & 0xffffu), sh.z), 0.f) + b2f(r.y & 0xffffu);
  float o3 = fmaxf(fmaf(sc.w, b2f(u.y >> 16), sh.w), 0.f) + b2f(r.y >> 16);
  uint2 o;
  o.x = (uint)f2b(o0) | ((uint)f2b(o1) << 16);
  o.y = (uint)f2b(o2) | ((uint)f2b(o3) << 16);
  return o;
}

// ---------------- fused mid: scatter (CSR fill) ∪ bnapply layer-0 ----------------
#define SCB 6250   // scatter blocks (1 edge/thread)
#define ABB 2048   // bnapply blocks (grid-stride)
__global__ __launch_bounds__(256) void k_mid(const int* __restrict__ row, const int* __restrict__ col,
                                             const int* __restrict__ rowptr, int* __restrict__ fill,
                                             int* __restrict__ srcbuf,
                                             const uint2* __restrict__ y, uint2* __restrict__ h,
                                             uint2* __restrict__ x0, const float* __restrict__ sums,
                                             const float* __restrict__ gamma,
                                             const float* __restrict__ beta) {
  __shared__ __align__(16) float ssl[256];
  if (blockIdx.x < SCB) {  // scatter
    int e = blockIdx.x * 256 + threadIdx.x;
    if (e < EE) {
      int c = col[e];
      int p = atomicAdd(&fill[c], 1);
      srcbuf[rowptr[c] + p] = row[e];
    }
    return;
  }
  bn_prologue(ssl, sums, gamma, beta);
  const float4* ss4 = (const float4*)ssl;
  for (int i = (blockIdx.x - SCB) * 256 + threadIdx.x; i < NN * 32; i += ABB * 256) {
    int j = i & 31;
    uint2 o = bn_elem(y[i], ss4[j], ss4[32 + j]);
    h[i] = o;
    x0[i] = o;
  }
}

// ---------------- bnapply (layers 1..3): h = relu(bn(y)) + x0 ----------------
__global__ __launch_bounds__(256) void k_bnapply(const uint2* __restrict__ y, uint2* __restrict__ h,
                                                 const uint2* __restrict__ res,
                                                 const float* __restrict__ sums,
                                                 const float* __restrict__ gamma,
                                                 const float* __restrict__ beta) {
  __shared__ __align__(16) float ssl[256];
  bn_prologue(ssl, sums, gamma, beta);
  const float4* ss4 = (const float4*)ssl;
  for (int i = blockIdx.x * 256 + threadIdx.x; i < NN * 32; i += ABB * 256) {
    int j = i & 31;
    h[i] = bn_elem_res(y[i], res[i], ss4[j], ss4[32 + j]);
  }
}

// ---------------- SPMM (gather, bf16 h, 8 edges in flight per wave) ----------------
// Wave = 1 node; 4 groups x 16 lanes; group g handles edges e0+g, e0+g+4, ... two per iter.
__global__ __launch_bounds__(256) void k_spmm(const uint4* __restrict__ h4, uint4* __restrict__ agg4,
                                              const int* __restrict__ rowptr,
                                              const int* __restrict__ srcbuf,
                                              const float* __restrict__ dinv) {
  int gid = blockIdx.x * 256 + threadIdx.x;
  int node = gid >> 6;
  if (node >= NN) return;
  int lane = threadIdx.x & 63;
  int g = lane >> 4, li = lane & 15;
  int e0 = rowptr[node], e1 = rowptr[node + 1];
  float acc[8];
#pragma unroll
  for (int j = 0; j < 8; ++j) acc[j] = 0.f;

  int eA = e0 + g;
  int sA = (eA < e1) ? srcbuf[eA] : -1;
  int sB = (eA + 4 < e1) ? srcbuf[eA + 4] : -1;
  while (eA < e1) {
    int eN = eA + 8;
    int sC = (eN < e1) ? srcbuf[eN] : -1;
    int sD = (eN + 4 < e1) ? srcbuf[eN + 4] : -1;
    int sBs = (sB >= 0) ? sB : sA;  // safe address; contribution masked by wB=0
    float wA = dinv[sA];
    uint4 vA = h4[(size_t)sA * 16 + li];
    float wB = dinv[sBs];
    uint4 vB = h4[(size_t)sBs * 16 + li];
    if (sB < 0) wB = 0.f;
    acc[0] = fmaf(wA, b2f(vA.x & 0xffffu), acc[0]);
    acc[1] = fmaf(wA, b2f(vA.x >> 16), acc[1]);
    acc[2] = fmaf(wA, b2f(vA.y & 0xffffu), acc[2]);
    acc[3] = fmaf(wA, b2f(vA.y >> 16), acc[3]);
    acc[4] = fmaf(wA, b2f(vA.z & 0xffffu), acc[4]);
    acc[5] = fmaf(wA, b2f(vA.z >> 16), acc[5]);
    acc[6] = fmaf(wA, b2f(vA.w & 0xffffu), acc[6]);
    acc[7] = fmaf(wA, b2f(vA.w >> 16), acc[7]);
    acc[0] = fmaf(wB, b2f(vB.x & 0xffffu), acc[0]);
    acc[1] = fmaf(wB, b2f(vB.x >> 16), acc[1]);
    acc[2] = fmaf(wB, b2f(vB.y & 0xffffu), acc[2]);
    acc[3] = fmaf(wB, b2f(vB.y >> 16), acc[3]);
    acc[4] = fmaf(wB, b2f(vB.z & 0xffffu), acc[4]);
    acc[5] = fmaf(wB, b2f(vB.z >> 16), acc[5]);
    acc[6] = fmaf(wB, b2f(vB.w & 0xffffu), acc[6]);
    acc[7] = fmaf(wB, b2f(vB.w >> 16), acc[7]);
    sA = sC;
    sB = sD;
    eA = eN;
  }
#pragma unroll
  for (int j = 0; j < 8; ++j) {
    acc[j] += __shfl_xor(acc[j], 16);
    acc[j] += __shfl_xor(acc[j], 32);
  }
  if (g == 0) {
    float dc = dinv[node];
    uint4 o;
    o.x = (uint)f2b(acc[0] * dc) | ((uint)f2b(acc[1] * dc) << 16);
    o.y = (uint)f2b(acc[2] * dc) | ((uint)f2b(acc[3] * dc) << 16);
    o.z = (uint)f2b(acc[4] * dc) | ((uint)f2b(acc[5] * dc) << 16);
    o.w = (uint)f2b(acc[6] * dc) | ((uint)f2b(acc[7] * dc) << 16);
    agg4[(size_t)node * 16 + li] = o;
  }
}

// ---------------- MFMA GEMM (128-row tiles): Y = A @ W^T + b, + BN stats ----------------
__global__ __launch_bounds__(256) void k_mgemm(const ushort* __restrict__ A,
                                               const ushort* __restrict__ W,
                                               const float* __restrict__ bias,
                                               ushort* __restrict__ Y,
                                               float* __restrict__ sums, int n) {
  __shared__ ushort As[128][136];
  __shared__ ushort Ws[128][136];
  __shared__ float ls1[4][128];
  __shared__ float ls2[4][128];
  int t = threadIdx.x;
  int w = t >> 6, l = t & 63;
  int quad = l >> 4, m = l & 15;
  int r0 = blockIdx.x * 128;
#pragma unroll
  for (int i = 0; i < 8; ++i) {
    int flat = (t + i * 256) * 8;
    int r = flat >> 7, k = flat & 127;
    uint4 v = make_uint4(0, 0, 0, 0);
    if (r0 + r < n) v = *(const uint4*)&A[(size_t)(r0 + r) * 128 + k];
    *(uint4*)&As[r][k] = v;
  }
#pragma unroll
  for (int i = 0; i < 8; ++i) {
    int flat = (t + i * 256) * 8;
    int r = flat >> 7, k = flat & 127;
    *(uint4*)&Ws[r][k] = *(const uint4*)&W[flat];
  }
  __syncthreads();
  bf16x8 af[2][4];
#pragma unroll
  for (int rt = 0; rt < 2; ++rt)
#pragma unroll
    for (int ks = 0; ks < 4; ++ks)
      af[rt][ks] = *(const bf16x8*)&As[w * 32 + rt * 16 + m][ks * 32 + quad * 8];
#pragma unroll
  for (int ct = 0; ct < 8; ++ct) {
    bf16x8 bfr[4];
#pragma unroll
    for (int ks = 0; ks < 4; ++ks) bfr[ks] = *(const bf16x8*)&Ws[ct * 16 + m][ks * 32 + quad * 8];
    int c = ct * 16 + m;  // C/D: col = lane&15, row = quad*4 + reg
    float b = bias[c];
    float s1 = 0.f, s2 = 0.f;
#pragma unroll
    for (int rt = 0; rt < 2; ++rt) {
      f32x4 acc = {0.f, 0.f, 0.f, 0.f};
#pragma unroll
      for (int ks = 0; ks < 4; ++ks)
        acc = __builtin_amdgcn_mfma_f32_16x16x32_bf16(af[rt][ks], bfr[ks], acc, 0, 0, 0);
      int rbase = r0 + w * 32 + rt * 16 + quad * 4;
#pragma unroll
      for (int i2 = 0; i2 < 4; ++i2) {
        int r = rbase + i2;
        if (r < n) {
          float v = acc[i2] + b;
          s1 += v;
          s2 += v * v;
          Y[(size_t)r * 128 + c] = f2b(v);
        }
      }
    }
    s1 += __shfl_xor(s1, 16);
    s1 += __shfl_xor(s1, 32);
    s2 += __shfl_xor(s2, 16);
    s2 += __shfl_xor(s2, 32);
    if (quad == 0) {
      ls1[w][c] = s1;
      ls2[w][c] = s2;
    }
  }
  __syncthreads();
  if (t < 128) {
    float a1 = ls1[0][t] + ls1[1][t] + ls1[2][t] + ls1[3][t];
    float a2 = ls2[0][t] + ls2[1][t] + ls2[2][t] + ls2[3][t];
    atomicAdd(&sums[t], a1);
    atomicAdd(&sums[128 + t], a2);
  }
}

// ---------------- classifier MFMA: out[N,40](f32) = h(bf16) @ cls_w^T(bf16) + cls_b ----------------
__global__ __launch_bounds__(256) void k_mcls(const ushort* __restrict__ A,
                                              const ushort* __restrict__ W,
                                              const float* __restrict__ bias,
                                              float* __restrict__ out, int n) {
  __shared__ ushort As[64][136];
  __shared__ ushort Ws[48][136];  // rows 40..47 zero
  int t = threadIdx.x;
  int w = t >> 6, l = t & 63;
  int quad = l >> 4, m = l & 15;
  int r0 = blockIdx.x * 64;
#pragma unroll
  for (int i = 0; i < 4; ++i) {
    int flat = (t + i * 256) * 8;
    int r = flat >> 7, k = flat & 127;
    uint4 v = make_uint4(0, 0, 0, 0);
    if (r0 + r < n) v = *(const uint4*)&A[(size_t)(r0 + r) * 128 + k];
    *(uint4*)&As[r][k] = v;
  }
#pragma unroll
  for (int i = 0; i < 3; ++i) {
    int slot = t + i * 256;
    int flat = slot * 8;
    int r = flat >> 7, k = flat & 127;
    uint4 v = make_uint4(0, 0, 0, 0);
    if (r < 40) v = *(const uint4*)&W[flat];
    *(uint4*)&Ws[r][k] = v;
  }
  __syncthreads();
  bf16x8 af[4];
#pragma unroll
  for (int ks = 0; ks < 4; ++ks)
    af[ks] = *(const bf16x8*)&As[w * 16 + m][ks * 32 + quad * 8];
#pragma unroll
  for (int ct = 0; ct < 3; ++ct) {
    f32x4 acc = {0.f, 0.f, 0.f, 0.f};
#pragma unroll
    for (int ks = 0; ks < 4; ++ks) {
      bf16x8 bf = *(const bf16x8*)&Ws[ct * 16 + m][ks * 32 + quad * 8];
      acc = __builtin_amdgcn_mfma_f32_16x16x32_bf16(af[ks], bf, acc, 0, 0, 0);
    }
    int c = ct * 16 + m;
    if (c < DOUT) {
      float b = bias[c];
      int rbase = r0 + w * 16 + quad * 4;
#pragma unroll
      for (int i = 0; i < 4; ++i) {
        int r = rbase + i;
        if (r < n) out[(size_t)r * DOUT + c] = acc[i] + b;
      }
    }
  }
}

// ---------------- launch ----------------
extern "C" void kernel_launch(void* const* d_in, const int* in_sizes, int n_in,
                              void* d_out, int out_size, void* d_ws, size_t ws_size,
                              hipStream_t stream) {
  const float* x      = (const float*)d_in[0];
  const int*   ei     = (const int*)d_in[1];
  const float* fc_w   = (const float*)d_in[2];
  const float* fc_b   = (const float*)d_in[3];
  const float* conv_w = (const float*)d_in[4];
  const float* conv_b = (const float*)d_in[5];
  const float* bn_g   = (const float*)d_in[6];
  const float* bn_b   = (const float*)d_in[7];
  const float* cls_w  = (const float*)d_in[8];
  const float* cls_b  = (const float*)d_in[9];
  const int* row  = ei;       // edge_index[0]
  const int* colv = ei + EE;  // edge_index[1]

  char* w = (char*)d_ws;
  auto alloc = [&](size_t bytes) {
    char* p = w;
    w += (bytes + 255) & ~(size_t)255;
    return p;
  };
  ushort* xb     = (ushort*)alloc((size_t)NN * 128 * 2);
  ushort* hb     = (ushort*)alloc((size_t)NN * 128 * 2);
  ushort* x0b    = (ushort*)alloc((size_t)NN * 128 * 2);
  ushort* aggb   = (ushort*)alloc((size_t)NN * 128 * 2);
  ushort* yb     = (ushort*)alloc((size_t)NN * 128 * 2);
  ushort* wb_fc  = (ushort*)alloc(128 * 128 * 2);
  ushort* wb_cv  = (ushort*)alloc(3 * 128 * 128 * 2);
  ushort* wb_cls = (ushort*)alloc(DOUT * 128 * 2);
  int*   srcbuf = (int*)alloc((size_t)EE * 4);
  int*   rowptr = (int*)alloc((size_t)(NN + 1) * 4);
  int*   bsums  = (int*)alloc(1024);
  int*   boffs  = (int*)alloc(1024);
  float* dinv   = (float*)alloc((size_t)NN * 4);
  // contiguous zero region: deg | fill | sums(4 layers x 256 floats)
  int*   deg    = (int*)alloc((size_t)NN * 4 + (size_t)NN * 4 + 1024 * 4);
  int*   fill   = deg + NN;
  float* sums   = (float*)(fill + NN);

  // fused casts + zero  (N4X+N4FC+N4CV+N4CLS+NZ2 = 3,318,176 items)
  k_front<<<(N4X + N4FC + N4CV + N4CLS + NZ2 + 255) / 256, 256, 0, stream>>>(
      (const float4*)x, (uint2*)xb, (const float4*)fc_w, (uint2*)wb_fc,
      (const float4*)conv_w, (uint2*)wb_cv, (const float4*)cls_w, (uint2*)wb_cls, (uint2*)deg);

  // CSR build
  k_degree<<<(EE + 255) / 256, 256, 0, stream>>>(colv, deg);
  k_scan1d<<<(NN + 1023) / 1024, 1024, 0, stream>>>(deg, rowptr, bsums, dinv, NN);
  k_scan2<<<1, 64, 0, stream>>>(bsums, boffs, (NN + 1023) / 1024);
  k_scan3<<<(NN + 255) / 256, 256, 0, stream>>>(rowptr, boffs, NN);

  int gblocks = (NN + 127) / 128;

  // layer 0 GEMM (independent of CSR) then fused scatter ∪ bnapply0
  k_mgemm<<<gblocks, 256, 0, stream>>>(xb, wb_fc, fc_b, yb, sums + 0 * 256, NN);
  k_mid<<<SCB + ABB, 256, 0, stream>>>(row, colv, rowptr, fill, srcbuf,
                                       (const uint2*)yb, (uint2*)hb, (uint2*)x0b,
                                       sums + 0 * 256, bn_g, bn_b);
  // conv layers
  for (int i = 0; i < 3; ++i) {
    k_spmm<<<(NN * 64 + 255) / 256, 256, 0, stream>>>((const uint4*)hb, (uint4*)aggb, rowptr, srcbuf, dinv);
    k_mgemm<<<gblocks, 256, 0, stream>>>(aggb, wb_cv + (size_t)i * 128 * 128, conv_b + (size_t)i * 128,
                                         yb, sums + (size_t)(i + 1) * 256, NN);
    k_bnapply<<<ABB, 256, 0, stream>>>((const uint2*)yb, (uint2*)hb, (const uint2*)x0b,
                                       sums + (size_t)(i + 1) * 256,
                                       bn_g + (size_t)(i + 1) * 128, bn_b + (size_t)(i + 1) * 128);
  }
  // classifier
  k_mcls<<<(NN + 63) / 64, 256, 0, stream>>>(hb, wb_cls, cls_b, (float*)d_out, NN);
}

// Round 7
// 630.084 us; speedup vs baseline: 2.4661x; 1.0695x over previous
//
#include <hip/hip_runtime.h>
#include <hip/hip_bf16.h>

#define NN 100000
#define EE 1600000
#define DH 128
#define DOUT 40
#define BN_EPS 1e-5f

typedef unsigned int uint;
typedef unsigned short ushort;
typedef __attribute__((ext_vector_type(8))) short bf16x8;
typedef __attribute__((ext_vector_type(4))) float f32x4;

#define NB 196     // ceil(NN/512) buckets of 512 nodes
#define PEB 8192   // edges per k_part block
#define ABB 2048   // bnapply grid-stride blocks

__device__ __forceinline__ float b2f(uint u) { return __uint_as_float(u << 16); }
__device__ __forceinline__ ushort f2b(float f) {
  __hip_bfloat16 b = __float2bfloat16(f);
  return *reinterpret_cast<ushort*>(&b);
}
__device__ __forceinline__ uint2 cast4(float4 v) {
  uint2 o;
  o.x = (uint)f2b(v.x) | ((uint)f2b(v.y) << 16);
  o.y = (uint)f2b(v.z) | ((uint)f2b(v.w) << 16);
  return o;
}

// ---------------- fused front: all fp32->bf16 casts + zero region ----------------
#define N4X   3200000   // x: NN*128/4
#define N4FC  4096      // 128*128/4
#define N4CV  12288     // 3*128*128/4
#define N4CLS 1280      // 40*128/4
#define NZ2   50640     // (NN + 1024 + 256)/2 uint2 zeros: deg | sums | gfill
__global__ __launch_bounds__(256) void k_front(const float4* __restrict__ xs, uint2* __restrict__ xd,
                                               const float4* __restrict__ w1s, uint2* __restrict__ w1d,
                                               const float4* __restrict__ w2s, uint2* __restrict__ w2d,
                                               const float4* __restrict__ w3s, uint2* __restrict__ w3d,
                                               uint2* __restrict__ zp) {
  int i = blockIdx.x * 256 + threadIdx.x;
  if (i < N4X) { xd[i] = cast4(xs[i]); return; }
  i -= N4X;
  if (i < N4FC) { w1d[i] = cast4(w1s[i]); return; }
  i -= N4FC;
  if (i < N4CV) { w2d[i] = cast4(w2s[i]); return; }
  i -= N4CV;
  if (i < N4CLS) { w3d[i] = cast4(w3s[i]); return; }
  i -= N4CLS;
  if (i < NZ2) zp[i] = make_uint2(0, 0);
}

// ---------------- CSR build ----------------
__global__ void k_degree(const int* __restrict__ col, int* __restrict__ deg) {
  int e = blockIdx.x * blockDim.x + threadIdx.x;
  if (e < EE) atomicAdd(&deg[col[e]], 1);
}

__global__ void k_scan1d(const int* __restrict__ deg, int* __restrict__ rowptr,
                         int* __restrict__ bsums, float* __restrict__ dinv, int n) {
  __shared__ int sm[1024];
  int i = blockIdx.x * 1024 + threadIdx.x;
  int v = (i < n) ? deg[i] : 0;
  if (i < n) dinv[i] = (v > 0) ? rsqrtf((float)v) : 0.f;
  sm[threadIdx.x] = v;
  __syncthreads();
  for (int off = 1; off < 1024; off <<= 1) {
    int t = (threadIdx.x >= off) ? sm[threadIdx.x - off] : 0;
    __syncthreads();
    sm[threadIdx.x] += t;
    __syncthreads();
  }
  if (i < n) rowptr[i + 1] = sm[threadIdx.x];
  if (threadIdx.x == 1023) bsums[blockIdx.x] = sm[1023];
}

__global__ void k_scan2(const int* __restrict__ bsums, int* __restrict__ boffs, int nb) {
  if (threadIdx.x == 0 && blockIdx.x == 0) {
    int run = 0;
    for (int b = 0; b < nb; ++b) { boffs[b] = run; run += bsums[b]; }
  }
}

__global__ void k_scan3(int* __restrict__ rowptr, const int* __restrict__ boffs, int n) {
  int i = blockIdx.x * blockDim.x + threadIdx.x;
  if (i == 0) rowptr[0] = 0;
  if (i < n) rowptr[i + 1] += boffs[i >> 10];
}

// ---------------- k_part: bucket-partition edges into pairbuf (CSR-bucket order) ----------------
// bucket b = dst>>9; bucket base = rowptr[b<<9]. Appends are dense per bucket -> full-line writes.
__global__ __launch_bounds__(256) void k_part(const int* __restrict__ row, const int* __restrict__ col,
                                              const int* __restrict__ rowptr, int* __restrict__ gfill,
                                              uint2* __restrict__ pairbuf) {
  __shared__ int lhist[NB];
  __shared__ int lgoff[NB];
  __shared__ int lbase[NB];
  int tid = threadIdx.x;
  for (int i = tid; i < NB; i += 256) lhist[i] = 0;
  __syncthreads();
  int base = blockIdx.x * PEB;
  int packed[32];
#pragma unroll
  for (int i = 0; i < 32; ++i) {
    int e = base + i * 256 + tid;
    packed[i] = -1;
    if (e < EE) {
      int b = col[e] >> 9;
      int p = atomicAdd(&lhist[b], 1);
      packed[i] = (b << 13) | p;  // p < 8192
    }
  }
  __syncthreads();
  for (int i = tid; i < NB; i += 256) {
    lgoff[i] = atomicAdd(&gfill[i], lhist[i]);
    lbase[i] = rowptr[i << 9];
  }
  __syncthreads();
#pragma unroll
  for (int i = 0; i < 32; ++i) {
    if (packed[i] >= 0) {
      int e = base + i * 256 + tid;
      int b = packed[i] >> 13, p = packed[i] & 8191;
      pairbuf[(size_t)lbase[b] + lgoff[b] + p] = make_uint2((uint)row[e], (uint)col[e]);
    }
  }
}

// ---------------- BN helpers ----------------
__device__ __forceinline__ void bn_prologue(float* ssl, const float* __restrict__ sums,
                                            const float* __restrict__ gamma,
                                            const float* __restrict__ beta) {
  int t = threadIdx.x;
  if (t < 128) {
    float mu = sums[t] * (1.f / NN);
    float var = sums[128 + t] * (1.f / NN) - mu * mu;
    float sc = gamma[t] * rsqrtf(var + BN_EPS);
    ssl[t] = sc;
    ssl[128 + t] = beta[t] - mu * sc;
  }
  __syncthreads();
}

__device__ __forceinline__ uint2 bn_elem(uint2 u, float4 sc, float4 sh) {
  float o0 = fmaxf(fmaf(sc.x, b2f(u.x & 0xffffu), sh.x), 0.f);
  float o1 = fmaxf(fmaf(sc.y, b2f(u.x >> 16), sh.y), 0.f);
  float o2 = fmaxf(fmaf(sc.z, b2f(u.y & 0xffffu), sh.z), 0.f);
  float o3 = fmaxf(fmaf(sc.w, b2f(u.y >> 16), sh.w), 0.f);
  uint2 o;
  o.x = (uint)f2b(o0) | ((uint)f2b(o1) << 16);
  o.y = (uint)f2b(o2) | ((uint)f2b(o3) << 16);
  return o;
}

__device__ __forceinline__ uint2 bn_elem_res(uint2 u, uint2 r, float4 sc, float4 sh) {
  float o0 = fmaxf(fmaf(sc.x, b2f(u.x & 0xffffu), sh.x), 0.f) + b2f(r.x & 0xffffu);
  float o1 = fmaxf(fmaf(sc.y, b2f(u.x >> 16), sh.y), 0.f) + b2f(r.x >> 16);
  float o2 = fmaxf(fmaf(sc.z, b2f(u.y & 0xffffu), sh.z), 0.f) + b2f(r.y & 0xffffu);
  float o3 = fmaxf(fmaf(sc.w, b2f(u.y >> 16), sh.w), 0.f) + b2f(r.y >> 16);
  uint2 o;
  o.x = (uint)f2b(o0) | ((uint)f2b(o1) << 16);
  o.y = (uint)f2b(o2) | ((uint)f2b(o3) << 16);
  return o;
}

// ---------------- k_mid: place (bucket -> srcbuf via LDS) ∪ bnapply layer-0 ----------------
__global__ __launch_bounds__(256) void k_mid(const uint2* __restrict__ pairbuf,
                                             const int* __restrict__ rowptr, int* __restrict__ srcbuf,
                                             const uint2* __restrict__ y, uint2* __restrict__ h,
                                             uint2* __restrict__ x0, const float* __restrict__ sums,
                                             const float* __restrict__ gamma,
                                             const float* __restrict__ beta) {
  __shared__ __align__(16) int smraw[13313];  // stage[12288] | fill[512] | rp[513]
  if (blockIdx.x < NB) {  // place
    int* stage = smraw;
    int* fill = smraw + 12288;
    int* rp = smraw + 12800;
    int b = blockIdx.x;
    int nstart = b << 9;
    int nend = min(nstart + 512, NN);
    int nloc = nend - nstart;
    for (int i = threadIdx.x; i <= nloc; i += 256) rp[i] = rowptr[nstart + i];
    for (int i = threadIdx.x; i < 512; i += 256) fill[i] = 0;
    __syncthreads();
    int estart = rp[0], eend = rp[nloc];
    int count = eend - estart;
    if (count <= 12288) {
      for (int i = threadIdx.x; i < count; i += 256) {
        uint2 pr = pairbuf[(size_t)estart + i];
        int loc = (int)pr.y - nstart;
        int p = atomicAdd(&fill[loc], 1);
        stage[rp[loc] - estart + p] = (int)pr.x;
      }
      __syncthreads();
      for (int i = threadIdx.x; i < count; i += 256) srcbuf[estart + i] = stage[i];
    } else {  // overflow fallback (statistically never)
      for (int i = threadIdx.x; i < count; i += 256) {
        uint2 pr = pairbuf[(size_t)estart + i];
        int loc = (int)pr.y - nstart;
        int p = atomicAdd(&fill[loc], 1);
        srcbuf[rp[loc] + p] = (int)pr.x;
      }
    }
    return;
  }
  // bnapply layer 0: h = relu(bn(y)), x0 = h
  float* ssl = (float*)smraw;
  bn_prologue(ssl, sums, gamma, beta);
  const float4* ss4 = (const float4*)ssl;
  for (int i = (blockIdx.x - NB) * 256 + threadIdx.x; i < NN * 32; i += ABB * 256) {
    int j = i & 31;
    uint2 o = bn_elem(y[i], ss4[j], ss4[32 + j]);
    h[i] = o;
    x0[i] = o;
  }
}

// ---------------- bnapply (layers 1..3): h = relu(bn(y)) + x0 ----------------
__global__ __launch_bounds__(256) void k_bnapply(const uint2* __restrict__ y, uint2* __restrict__ h,
                                                 const uint2* __restrict__ res,
                                                 const float* __restrict__ sums,
                                                 const float* __restrict__ gamma,
                                                 const float* __restrict__ beta) {
  __shared__ __align__(16) float ssl[256];
  bn_prologue(ssl, sums, gamma, beta);
  const float4* ss4 = (const float4*)ssl;
  for (int i = blockIdx.x * 256 + threadIdx.x; i < NN * 32; i += ABB * 256) {
    int j = i & 31;
    h[i] = bn_elem_res(y[i], res[i], ss4[j], ss4[32 + j]);
  }
}

// ---------------- SPMM: 16 gathers in flight per wave (4 groups x 4-deep unroll) ----------------
__device__ __forceinline__ void fmac8(float* acc, uint4 v, float wgt) {
  acc[0] = fmaf(wgt, b2f(v.x & 0xffffu), acc[0]);
  acc[1] = fmaf(wgt, b2f(v.x >> 16), acc[1]);
  acc[2] = fmaf(wgt, b2f(v.y & 0xffffu), acc[2]);
  acc[3] = fmaf(wgt, b2f(v.y >> 16), acc[3]);
  acc[4] = fmaf(wgt, b2f(v.z & 0xffffu), acc[4]);
  acc[5] = fmaf(wgt, b2f(v.z >> 16), acc[5]);
  acc[6] = fmaf(wgt, b2f(v.w & 0xffffu), acc[6]);
  acc[7] = fmaf(wgt, b2f(v.w >> 16), acc[7]);
}

__global__ __launch_bounds__(256) void k_spmm(const uint4* __restrict__ h4, uint4* __restrict__ agg4,
                                              const int* __restrict__ rowptr,
                                              const int* __restrict__ srcbuf,
                                              const float* __restrict__ dinv) {
  int gid = blockIdx.x * 256 + threadIdx.x;
  int node = gid >> 6;
  if (node >= NN) return;
  int lane = threadIdx.x & 63;
  int g = lane >> 4, li = lane & 15;
  int e0 = rowptr[node], e1 = rowptr[node + 1];
  float acc[8];
#pragma unroll
  for (int j = 0; j < 8; ++j) acc[j] = 0.f;

  int eA = e0 + g;
  int s0 = (eA < e1) ? srcbuf[eA] : -1;
  int s1 = (eA + 4 < e1) ? srcbuf[eA + 4] : -1;
  int s2 = (eA + 8 < e1) ? srcbuf[eA + 8] : -1;
  int s3 = (eA + 12 < e1) ? srcbuf[eA + 12] : -1;
  while (eA < e1) {
    int eN = eA + 16;
    int t0 = (eN < e1) ? srcbuf[eN] : -1;
    int t1 = (eN + 4 < e1) ? srcbuf[eN + 4] : -1;
    int t2 = (eN + 8 < e1) ? srcbuf[eN + 8] : -1;
    int t3 = (eN + 12 < e1) ? srcbuf[eN + 12] : -1;
    int a1 = (s1 >= 0) ? s1 : s0;
    int a2 = (s2 >= 0) ? s2 : s0;
    int a3 = (s3 >= 0) ? s3 : s0;
    float w0 = dinv[s0];
    uint4 v0 = h4[(size_t)s0 * 16 + li];
    float w1 = (s1 >= 0) ? dinv[a1] : 0.f;
    uint4 v1 = h4[(size_t)a1 * 16 + li];
    float w2 = (s2 >= 0) ? dinv[a2] : 0.f;
    uint4 v2 = h4[(size_t)a2 * 16 + li];
    float w3 = (s3 >= 0) ? dinv[a3] : 0.f;
    uint4 v3 = h4[(size_t)a3 * 16 + li];
    fmac8(acc, v0, w0);
    fmac8(acc, v1, w1);
    fmac8(acc, v2, w2);
    fmac8(acc, v3, w3);
    s0 = t0; s1 = t1; s2 = t2; s3 = t3;
    eA = eN;
  }
#pragma unroll
  for (int j = 0; j < 8; ++j) {
    acc[j] += __shfl_xor(acc[j], 16);
    acc[j] += __shfl_xor(acc[j], 32);
  }
  if (g == 0) {
    float dc = dinv[node];
    uint4 o;
    o.x = (uint)f2b(acc[0] * dc) | ((uint)f2b(acc[1] * dc) << 16);
    o.y = (uint)f2b(acc[2] * dc) | ((uint)f2b(acc[3] * dc) << 16);
    o.z = (uint)f2b(acc[4] * dc) | ((uint)f2b(acc[5] * dc) << 16);
    o.w = (uint)f2b(acc[6] * dc) | ((uint)f2b(acc[7] * dc) << 16);
    agg4[(size_t)node * 16 + li] = o;
  }
}

// ---------------- MFMA GEMM (128-row tiles): Y = A @ W^T + b, + BN stats ----------------
__global__ __launch_bounds__(256) void k_mgemm(const ushort* __restrict__ A,
                                               const ushort* __restrict__ W,
                                               const float* __restrict__ bias,
                                               ushort* __restrict__ Y,
                                               float* __restrict__ sums, int n) {
  __shared__ ushort As[128][136];
  __shared__ ushort Ws[128][136];
  __shared__ float ls1[4][128];
  __shared__ float ls2[4][128];
  int t = threadIdx.x;
  int w = t >> 6, l = t & 63;
  int quad = l >> 4, m = l & 15;
  int r0 = blockIdx.x * 128;
#pragma unroll
  for (int i = 0; i < 8; ++i) {
    int flat = (t + i * 256) * 8;
    int r = flat >> 7, k = flat & 127;
    uint4 v = make_uint4(0, 0, 0, 0);
    if (r0 + r < n) v = *(const uint4*)&A[(size_t)(r0 + r) * 128 + k];
    *(uint4*)&As[r][k] = v;
  }
#pragma unroll
  for (int i = 0; i < 8; ++i) {
    int flat = (t + i * 256) * 8;
    int r = flat >> 7, k = flat & 127;
    *(uint4*)&Ws[r][k] = *(const uint4*)&W[flat];
  }
  __syncthreads();
  bf16x8 af[2][4];
#pragma unroll
  for (int rt = 0; rt < 2; ++rt)
#pragma unroll
    for (int ks = 0; ks < 4; ++ks)
      af[rt][ks] = *(const bf16x8*)&As[w * 32 + rt * 16 + m][ks * 32 + quad * 8];
#pragma unroll
  for (int ct = 0; ct < 8; ++ct) {
    bf16x8 bfr[4];
#pragma unroll
    for (int ks = 0; ks < 4; ++ks) bfr[ks] = *(const bf16x8*)&Ws[ct * 16 + m][ks * 32 + quad * 8];
    int c = ct * 16 + m;  // C/D: col = lane&15, row = quad*4 + reg
    float b = bias[c];
    float s1 = 0.f, s2 = 0.f;
#pragma unroll
    for (int rt = 0; rt < 2; ++rt) {
      f32x4 acc = {0.f, 0.f, 0.f, 0.f};
#pragma unroll
      for (int ks = 0; ks < 4; ++ks)
        acc = __builtin_amdgcn_mfma_f32_16x16x32_bf16(af[rt][ks], bfr[ks], acc, 0, 0, 0);
      int rbase = r0 + w * 32 + rt * 16 + quad * 4;
#pragma unroll
      for (int i2 = 0; i2 < 4; ++i2) {
        int r = rbase + i2;
        if (r < n) {
          float v = acc[i2] + b;
          s1 += v;
          s2 += v * v;
          Y[(size_t)r * 128 + c] = f2b(v);
        }
      }
    }
    s1 += __shfl_xor(s1, 16);
    s1 += __shfl_xor(s1, 32);
    s2 += __shfl_xor(s2, 16);
    s2 += __shfl_xor(s2, 32);
    if (quad == 0) {
      ls1[w][c] = s1;
      ls2[w][c] = s2;
    }
  }
  __syncthreads();
  if (t < 128) {
    float a1 = ls1[0][t] + ls1[1][t] + ls1[2][t] + ls1[3][t];
    float a2 = ls2[0][t] + ls2[1][t] + ls2[2][t] + ls2[3][t];
    atomicAdd(&sums[t], a1);
    atomicAdd(&sums[128 + t], a2);
  }
}

// ---------------- classifier MFMA: out[N,40](f32) = h(bf16) @ cls_w^T(bf16) + cls_b ----------------
__global__ __launch_bounds__(256) void k_mcls(const ushort* __restrict__ A,
                                              const ushort* __restrict__ W,
                                              const float* __restrict__ bias,
                                              float* __restrict__ out, int n) {
  __shared__ ushort As[64][136];
  __shared__ ushort Ws[48][136];  // rows 40..47 zero
  int t = threadIdx.x;
  int w = t >> 6, l = t & 63;
  int quad = l >> 4, m = l & 15;
  int r0 = blockIdx.x * 64;
#pragma unroll
  for (int i = 0; i < 4; ++i) {
    int flat = (t + i * 256) * 8;
    int r = flat >> 7, k = flat & 127;
    uint4 v = make_uint4(0, 0, 0, 0);
    if (r0 + r < n) v = *(const uint4*)&A[(size_t)(r0 + r) * 128 + k];
    *(uint4*)&As[r][k] = v;
  }
#pragma unroll
  for (int i = 0; i < 3; ++i) {
    int slot = t + i * 256;
    int flat = slot * 8;
    int r = flat >> 7, k = flat & 127;
    uint4 v = make_uint4(0, 0, 0, 0);
    if (r < 40) v = *(const uint4*)&W[flat];
    *(uint4*)&Ws[r][k] = v;
  }
  __syncthreads();
  bf16x8 af[4];
#pragma unroll
  for (int ks = 0; ks < 4; ++ks)
    af[ks] = *(const bf16x8*)&As[w * 16 + m][ks * 32 + quad * 8];
#pragma unroll
  for (int ct = 0; ct < 3; ++ct) {
    f32x4 acc = {0.f, 0.f, 0.f, 0.f};
#pragma unroll
    for (int ks = 0; ks < 4; ++ks) {
      bf16x8 bf = *(const bf16x8*)&Ws[ct * 16 + m][ks * 32 + quad * 8];
      acc = __builtin_amdgcn_mfma_f32_16x16x32_bf16(af[ks], bf, acc, 0, 0, 0);
    }
    int c = ct * 16 + m;
    if (c < DOUT) {
      float b = bias[c];
      int rbase = r0 + w * 16 + quad * 4;
#pragma unroll
      for (int i = 0; i < 4; ++i) {
        int r = rbase + i;
        if (r < n) out[(size_t)r * DOUT + c] = acc[i] + b;
      }
    }
  }
}

// ---------------- launch ----------------
extern "C" void kernel_launch(void* const* d_in, const int* in_sizes, int n_in,
                              void* d_out, int out_size, void* d_ws, size_t ws_size,
                              hipStream_t stream) {
  const float* x      = (const float*)d_in[0];
  const int*   ei     = (const int*)d_in[1];
  const float* fc_w   = (const float*)d_in[2];
  const float* fc_b   = (const float*)d_in[3];
  const float* conv_w = (const float*)d_in[4];
  const float* conv_b = (const float*)d_in[5];
  const float* bn_g   = (const float*)d_in[6];
  const float* bn_b   = (const float*)d_in[7];
  const float* cls_w  = (const float*)d_in[8];
  const float* cls_b  = (const float*)d_in[9];
  const int* row  = ei;       // edge_index[0]
  const int* colv = ei + EE;  // edge_index[1]

  char* w = (char*)d_ws;
  auto alloc = [&](size_t bytes) {
    char* p = w;
    w += (bytes + 255) & ~(size_t)255;
    return p;
  };
  ushort* xb     = (ushort*)alloc((size_t)NN * 128 * 2);
  ushort* hb     = (ushort*)alloc((size_t)NN * 128 * 2);
  ushort* x0b    = (ushort*)alloc((size_t)NN * 128 * 2);
  ushort* aggb   = (ushort*)alloc((size_t)NN * 128 * 2);
  ushort* yb     = (ushort*)alloc((size_t)NN * 128 * 2);
  ushort* wb_fc  = (ushort*)alloc(128 * 128 * 2);
  ushort* wb_cv  = (ushort*)alloc(3 * 128 * 128 * 2);
  ushort* wb_cls = (ushort*)alloc(DOUT * 128 * 2);
  int*   srcbuf  = (int*)alloc((size_t)EE * 4);
  uint2* pairbuf = (uint2*)alloc((size_t)EE * 8);
  int*   rowptr  = (int*)alloc((size_t)(NN + 1) * 4);
  int*   bsums   = (int*)alloc(1024);
  int*   boffs   = (int*)alloc(1024);
  float* dinv    = (float*)alloc((size_t)NN * 4);
  // contiguous zero region: deg[NN] | sums(1024 floats) | gfill(256 ints)
  int*   deg    = (int*)alloc((size_t)NN * 4 + 1024 * 4 + 256 * 4);
  float* sums   = (float*)(deg + NN);
  int*   gfill  = (int*)(sums + 1024);

  // fused casts + zero
  k_front<<<(N4X + N4FC + N4CV + N4CLS + NZ2 + 255) / 256, 256, 0, stream>>>(
      (const float4*)x, (uint2*)xb, (const float4*)fc_w, (uint2*)wb_fc,
      (const float4*)conv_w, (uint2*)wb_cv, (const float4*)cls_w, (uint2*)wb_cls, (uint2*)deg);

  // CSR build: degree -> scan -> bucket partition
  k_degree<<<(EE + 255) / 256, 256, 0, stream>>>(colv, deg);
  k_scan1d<<<(NN + 1023) / 1024, 1024, 0, stream>>>(deg, rowptr, bsums, dinv, NN);
  k_scan2<<<1, 64, 0, stream>>>(bsums, boffs, (NN + 1023) / 1024);
  k_scan3<<<(NN + 255) / 256, 256, 0, stream>>>(rowptr, boffs, NN);
  k_part<<<(EE + PEB - 1) / PEB, 256, 0, stream>>>(row, colv, rowptr, gfill, pairbuf);

  int gblocks = (NN + 127) / 128;

  // layer 0 GEMM, then fused place ∪ bnapply0
  k_mgemm<<<gblocks, 256, 0, stream>>>(xb, wb_fc, fc_b, yb, sums + 0 * 256, NN);
  k_mid<<<NB + ABB, 256, 0, stream>>>(pairbuf, rowptr, srcbuf,
                                      (const uint2*)yb, (uint2*)hb, (uint2*)x0b,
                                      sums + 0 * 256, bn_g, bn_b);
  // conv layers
  for (int i = 0; i < 3; ++i) {
    k_spmm<<<(NN * 64 + 255) / 256, 256, 0, stream>>>((const uint4*)hb, (uint4*)aggb, rowptr, srcbuf, dinv);
    k_mgemm<<<gblocks, 256, 0, stream>>>(aggb, wb_cv + (size_t)i * 128 * 128, conv_b + (size_t)i * 128,
                                         yb, sums + (size_t)(i + 1) * 256, NN);
    k_bnapply<<<ABB, 256, 0, stream>>>((const uint2*)yb, (uint2*)hb, (const uint2*)x0b,
                                       sums + (size_t)(i + 1) * 256,
                                       bn_g + (size_t)(i + 1) * 128, bn_b + (size_t)(i + 1) * 128);
  }
  // classifier
  k_mcls<<<(NN + 63) / 64, 256, 0, stream>>>(hb, wb_cls, cls_b, (float*)d_out, NN);
}

// Round 8
// 573.273 us; speedup vs baseline: 2.7104x; 1.0991x over previous
//
#include <hip/hip_runtime.h>
#include <hip/hip_bf16.h>

#define NN 100000
#define EE 1600000
#define DH 128
#define DOUT 40
#define BN_EPS 1e-5f

typedef unsigned int uint;
typedef unsigned short ushort;
typedef __attribute__((ext_vector_type(8))) short bf16x8;
typedef __attribute__((ext_vector_type(4))) float f32x4;

#define NB 196     // ceil(NN/512) buckets of 512 nodes
#define NPB 196    // partition/hist blocks: ceil(EE/PEB)
#define PEB 8192   // edges per partition block
#define ABB 2048   // bnapply grid-stride blocks
#define NFB 72     // k_front cast/zero blocks (18274 items / 256)

__device__ __forceinline__ float b2f(uint u) { return __uint_as_float(u << 16); }
__device__ __forceinline__ ushort f2b(float f) {
  __hip_bfloat16 b = __float2bfloat16(f);
  return *reinterpret_cast<ushort*>(&b);
}
__device__ __forceinline__ uint2 cast4(float4 v) {
  uint2 o;
  o.x = (uint)f2b(v.x) | ((uint)f2b(v.y) << 16);
  o.y = (uint)f2b(v.z) | ((uint)f2b(v.w) << 16);
  return o;
}

// ---------------- k_front: weight casts + zero region + bucket histograms ----------------
#define N4FC  4096      // 128*128/4
#define N4CV  12288     // 3*128*128/4
#define N4CLS 1280      // 40*128/4
#define NZ2   610       // (1024 sums + 196 gfill) / 2 uint2 zeros
__global__ __launch_bounds__(256) void k_front(const float4* __restrict__ w1s, uint2* __restrict__ w1d,
                                               const float4* __restrict__ w2s, uint2* __restrict__ w2d,
                                               const float4* __restrict__ w3s, uint2* __restrict__ w3d,
                                               uint2* __restrict__ zp,
                                               const int* __restrict__ col, int* __restrict__ hist_mat) {
  __shared__ int lh[NB];
  if (blockIdx.x < NFB) {
    int i = blockIdx.x * 256 + threadIdx.x;
    if (i < N4FC) { w1d[i] = cast4(w1s[i]); return; }
    i -= N4FC;
    if (i < N4CV) { w2d[i] = cast4(w2s[i]); return; }
    i -= N4CV;
    if (i < N4CLS) { w3d[i] = cast4(w3s[i]); return; }
    i -= N4CLS;
    if (i < NZ2) zp[i] = make_uint2(0, 0);
    return;
  }
  // bucket histogram block
  int hb = blockIdx.x - NFB;
  int tid = threadIdx.x;
  for (int i = tid; i < NB; i += 256) lh[i] = 0;
  __syncthreads();
  int base = hb * PEB;
#pragma unroll
  for (int i = 0; i < 32; ++i) {
    int e = base + i * 256 + tid;
    if (e < EE) atomicAdd(&lh[col[e] >> 9], 1);
  }
  __syncthreads();
  for (int i = tid; i < NB; i += 256) hist_mat[hb * NB + i] = lh[i];
}

// ---------------- k_bscan: column-sum hist matrix + exclusive scan -> bbase ----------------
__global__ void k_bscan(const int* __restrict__ hist_mat, int* __restrict__ bbase) {
  __shared__ int sm[256];
  int j = threadIdx.x;
  int tot = 0;
  if (j < NB)
    for (int i = 0; i < NPB; ++i) tot += hist_mat[i * NB + j];
  sm[j] = tot;
  __syncthreads();
  for (int off = 1; off < 256; off <<= 1) {
    int t = (j >= off) ? sm[j - off] : 0;
    __syncthreads();
    sm[j] += t;
    __syncthreads();
  }
  if (j < NB) bbase[j] = sm[j] - tot;  // exclusive
  if (j == NB - 1) bbase[NB] = sm[j];  // == EE
}

// ---------------- k_part: bucket-partition edges into packed pairbuf ----------------
// pairbuf entry = (loc<<17) | row,  loc = col & 511. Appends dense per bucket.
__global__ __launch_bounds__(256) void k_part(const int* __restrict__ row, const int* __restrict__ col,
                                              const int* __restrict__ bbase, int* __restrict__ gfill,
                                              uint* __restrict__ pairbuf) {
  __shared__ int lhist[NB];
  __shared__ int lgoff[NB];
  __shared__ int lbase[NB];
  int tid = threadIdx.x;
  for (int i = tid; i < NB; i += 256) lhist[i] = 0;
  __syncthreads();
  int base = blockIdx.x * PEB;
  int packed[32];
#pragma unroll
  for (int i = 0; i < 32; ++i) {
    int e = base + i * 256 + tid;
    packed[i] = -1;
    if (e < EE) {
      int c = col[e];
      int b = c >> 9, loc = c & 511;
      int p = atomicAdd(&lhist[b], 1);
      packed[i] = (b << 22) | (loc << 13) | p;  // b<256, loc<512, p<8192
    }
  }
  __syncthreads();
  for (int i = tid; i < NB; i += 256) {
    lgoff[i] = atomicAdd(&gfill[i], lhist[i]);
    lbase[i] = bbase[i];
  }
  __syncthreads();
#pragma unroll
  for (int i = 0; i < 32; ++i) {
    if (packed[i] >= 0) {
      int e = base + i * 256 + tid;
      int b = packed[i] >> 22, loc = (packed[i] >> 13) & 511, p = packed[i] & 8191;
      pairbuf[(size_t)lbase[b] + lgoff[b] + p] = ((uint)loc << 17) | (uint)row[e];
    }
  }
}

// ---------------- BN helpers ----------------
__device__ __forceinline__ void bn_prologue(float* ssl, const float* __restrict__ sums,
                                            const float* __restrict__ gamma,
                                            const float* __restrict__ beta) {
  int t = threadIdx.x;
  if (t < 128) {
    float mu = sums[t] * (1.f / NN);
    float var = sums[128 + t] * (1.f / NN) - mu * mu;
    float sc = gamma[t] * rsqrtf(var + BN_EPS);
    ssl[t] = sc;
    ssl[128 + t] = beta[t] - mu * sc;
  }
  __syncthreads();
}

__device__ __forceinline__ uint2 bn_elem(uint2 u, float4 sc, float4 sh) {
  float o0 = fmaxf(fmaf(sc.x, b2f(u.x & 0xffffu), sh.x), 0.f);
  float o1 = fmaxf(fmaf(sc.y, b2f(u.x >> 16), sh.y), 0.f);
  float o2 = fmaxf(fmaf(sc.z, b2f(u.y & 0xffffu), sh.z), 0.f);
  float o3 = fmaxf(fmaf(sc.w, b2f(u.y >> 16), sh.w), 0.f);
  uint2 o;
  o.x = (uint)f2b(o0) | ((uint)f2b(o1) << 16);
  o.y = (uint)f2b(o2) | ((uint)f2b(o3) << 16);
  return o;
}

__device__ __forceinline__ uint2 bn_elem_res(uint2 u, uint2 r, float4 sc, float4 sh) {
  float o0 = fmaxf(fmaf(sc.x, b2f(u.x & 0xffffu), sh.x), 0.f) + b2f(r.x & 0xffffu);
  float o1 = fmaxf(fmaf(sc.y, b2f(u.x >> 16), sh.y), 0.f) + b2f(r.x >> 16);
  float o2 = fmaxf(fmaf(sc.z, b2f(u.y & 0xffffu), sh.z), 0.f) + b2f(r.y & 0xffffu);
  float o3 = fmaxf(fmaf(sc.w, b2f(u.y >> 16), sh.w), 0.f) + b2f(r.y >> 16);
  uint2 o;
  o.x = (uint)f2b(o0) | ((uint)f2b(o1) << 16);
  o.y = (uint)f2b(o2) | ((uint)f2b(o3) << 16);
  return o;
}

// ---------------- k_mid: place (deg+scan+rowptr+dinv+srcbuf per bucket) ∪ bnapply layer-0 ----------------
__global__ __launch_bounds__(256) void k_mid(const uint* __restrict__ pairbuf,
                                             const int* __restrict__ bbase,
                                             int* __restrict__ rowptr, float* __restrict__ dinv,
                                             int* __restrict__ srcbuf,
                                             const uint2* __restrict__ y, uint2* __restrict__ h,
                                             uint2* __restrict__ x0, const float* __restrict__ sums,
                                             const float* __restrict__ gamma,
                                             const float* __restrict__ beta) {
  __shared__ __align__(16) int smraw[13569];  // stage[12288] | dega[512] | lrp[513] | ssum[256]
  if (blockIdx.x < NB) {  // place
    int* stage = smraw;
    int* dega = smraw + 12288;
    int* lrp = smraw + 12800;
    int* ssum = smraw + 13313;
    int tid = threadIdx.x;
    int b = blockIdx.x;
    int nstart = b << 9;
    int nloc = min(nstart + 512, NN) - nstart;
    int estart = bbase[b];
    int count = bbase[b + 1] - estart;
    // pass 1: per-node degree histogram
    dega[tid] = 0;
    dega[256 + tid] = 0;
    __syncthreads();
    for (int i = tid; i < count; i += 256) atomicAdd(&dega[pairbuf[(size_t)estart + i] >> 17], 1);
    __syncthreads();
    // local exclusive scan of dega[512] (pairwise + 256-wide Hillis-Steele)
    int d0 = dega[2 * tid], d1 = dega[2 * tid + 1];
    ssum[tid] = d0 + d1;
    __syncthreads();
    for (int off = 1; off < 256; off <<= 1) {
      int t2 = (tid >= off) ? ssum[tid - off] : 0;
      __syncthreads();
      ssum[tid] += t2;
      __syncthreads();
    }
    int incl = ssum[tid];
    int ex = incl - (d0 + d1);
    lrp[2 * tid] = ex;
    lrp[2 * tid + 1] = ex + d0;
    if (tid == 255) lrp[512] = incl;
    __syncthreads();
    // write rowptr & dinv
    for (int i = tid; i < nloc; i += 256) {
      rowptr[nstart + i] = estart + lrp[i];
      int dg = dega[i];
      dinv[nstart + i] = (dg > 0) ? rsqrtf((float)dg) : 0.f;
    }
    if (b == NB - 1 && tid == 0) rowptr[NN] = estart + count;
    // reset dega -> fill
    __syncthreads();
    dega[tid] = 0;
    dega[256 + tid] = 0;
    __syncthreads();
    // pass 2: place
    if (count <= 12288) {
      for (int i = tid; i < count; i += 256) {
        uint v = pairbuf[(size_t)estart + i];
        int loc = v >> 17;
        int p = atomicAdd(&dega[loc], 1);
        stage[lrp[loc] + p] = (int)(v & 0x1FFFFu);
      }
      __syncthreads();
      for (int i = tid; i < count; i += 256) srcbuf[estart + i] = stage[i];
    } else {  // overflow fallback (statistically never)
      for (int i = tid; i < count; i += 256) {
        uint v = pairbuf[(size_t)estart + i];
        int loc = v >> 17;
        int p = atomicAdd(&dega[loc], 1);
        srcbuf[estart + lrp[loc] + p] = (int)(v & 0x1FFFFu);
      }
    }
    return;
  }
  // bnapply layer 0: h = relu(bn(y)), x0 = h
  float* ssl = (float*)smraw;
  bn_prologue(ssl, sums, gamma, beta);
  const float4* ss4 = (const float4*)ssl;
  for (int i = (blockIdx.x - NB) * 256 + threadIdx.x; i < NN * 32; i += ABB * 256) {
    int j = i & 31;
    uint2 o = bn_elem(y[i], ss4[j], ss4[32 + j]);
    h[i] = o;
    x0[i] = o;
  }
}

// ---------------- bnapply (layers 1..3): h = relu(bn(y)) + x0 ----------------
__global__ __launch_bounds__(256) void k_bnapply(const uint2* __restrict__ y, uint2* __restrict__ h,
                                                 const uint2* __restrict__ res,
                                                 const float* __restrict__ sums,
                                                 const float* __restrict__ gamma,
                                                 const float* __restrict__ beta) {
  __shared__ __align__(16) float ssl[256];
  bn_prologue(ssl, sums, gamma, beta);
  const float4* ss4 = (const float4*)ssl;
  for (int i = blockIdx.x * 256 + threadIdx.x; i < NN * 32; i += ABB * 256) {
    int j = i & 31;
    h[i] = bn_elem_res(y[i], res[i], ss4[j], ss4[32 + j]);
  }
}

// ---------------- SPMM: 16 gathers in flight per wave (4 groups x 4-deep unroll) ----------------
__device__ __forceinline__ void fmac8(float* acc, uint4 v, float wgt) {
  acc[0] = fmaf(wgt, b2f(v.x & 0xffffu), acc[0]);
  acc[1] = fmaf(wgt, b2f(v.x >> 16), acc[1]);
  acc[2] = fmaf(wgt, b2f(v.y & 0xffffu), acc[2]);
  acc[3] = fmaf(wgt, b2f(v.y >> 16), acc[3]);
  acc[4] = fmaf(wgt, b2f(v.z & 0xffffu), acc[4]);
  acc[5] = fmaf(wgt, b2f(v.z >> 16), acc[5]);
  acc[6] = fmaf(wgt, b2f(v.w & 0xffffu), acc[6]);
  acc[7] = fmaf(wgt, b2f(v.w >> 16), acc[7]);
}

__global__ __launch_bounds__(256) void k_spmm(const uint4* __restrict__ h4, uint4* __restrict__ agg4,
                                              const int* __restrict__ rowptr,
                                              const int* __restrict__ srcbuf,
                                              const float* __restrict__ dinv) {
  int gid = blockIdx.x * 256 + threadIdx.x;
  int node = gid >> 6;
  if (node >= NN) return;
  int lane = threadIdx.x & 63;
  int g = lane >> 4, li = lane & 15;
  int e0 = rowptr[node], e1 = rowptr[node + 1];
  float acc[8];
#pragma unroll
  for (int j = 0; j < 8; ++j) acc[j] = 0.f;

  int eA = e0 + g;
  int s0 = (eA < e1) ? srcbuf[eA] : -1;
  int s1 = (eA + 4 < e1) ? srcbuf[eA + 4] : -1;
  int s2 = (eA + 8 < e1) ? srcbuf[eA + 8] : -1;
  int s3 = (eA + 12 < e1) ? srcbuf[eA + 12] : -1;
  while (eA < e1) {
    int eN = eA + 16;
    int t0 = (eN < e1) ? srcbuf[eN] : -1;
    int t1 = (eN + 4 < e1) ? srcbuf[eN + 4] : -1;
    int t2 = (eN + 8 < e1) ? srcbuf[eN + 8] : -1;
    int t3 = (eN + 12 < e1) ? srcbuf[eN + 12] : -1;
    int a1 = (s1 >= 0) ? s1 : s0;
    int a2 = (s2 >= 0) ? s2 : s0;
    int a3 = (s3 >= 0) ? s3 : s0;
    float w0 = dinv[s0];
    uint4 v0 = h4[(size_t)s0 * 16 + li];
    float w1 = (s1 >= 0) ? dinv[a1] : 0.f;
    uint4 v1 = h4[(size_t)a1 * 16 + li];
    float w2 = (s2 >= 0) ? dinv[a2] : 0.f;
    uint4 v2 = h4[(size_t)a2 * 16 + li];
    float w3 = (s3 >= 0) ? dinv[a3] : 0.f;
    uint4 v3 = h4[(size_t)a3 * 16 + li];
    fmac8(acc, v0, w0);
    fmac8(acc, v1, w1);
    fmac8(acc, v2, w2);
    fmac8(acc, v3, w3);
    s0 = t0; s1 = t1; s2 = t2; s3 = t3;
    eA = eN;
  }
#pragma unroll
  for (int j = 0; j < 8; ++j) {
    acc[j] += __shfl_xor(acc[j], 16);
    acc[j] += __shfl_xor(acc[j], 32);
  }
  if (g == 0) {
    float dc = dinv[node];
    uint4 o;
    o.x = (uint)f2b(acc[0] * dc) | ((uint)f2b(acc[1] * dc) << 16);
    o.y = (uint)f2b(acc[2] * dc) | ((uint)f2b(acc[3] * dc) << 16);
    o.z = (uint)f2b(acc[4] * dc) | ((uint)f2b(acc[5] * dc) << 16);
    o.w = (uint)f2b(acc[6] * dc) | ((uint)f2b(acc[7] * dc) << 16);
    agg4[(size_t)node * 16 + li] = o;
  }
}

// ---------------- MFMA GEMM (128-row tiles): Y = A @ W^T + b, + BN stats ----------------
// TA = ushort (bf16 A) or float (fp32 A, converted during LDS staging)
template <typename TA>
__global__ __launch_bounds__(256) void k_mgemm(const TA* __restrict__ A,
                                               const ushort* __restrict__ W,
                                               const float* __restrict__ bias,
                                               ushort* __restrict__ Y,
                                               float* __restrict__ sums, int n) {
  __shared__ ushort As[128][136];
  __shared__ ushort Ws[128][136];
  __shared__ float ls1[4][128];
  __shared__ float ls2[4][128];
  int t = threadIdx.x;
  int w = t >> 6, l = t & 63;
  int quad = l >> 4, m = l & 15;
  int r0 = blockIdx.x * 128;
  if constexpr (sizeof(TA) == 4) {
#pragma unroll
    for (int i = 0; i < 16; ++i) {
      int flat = (t + i * 256) * 4;
      int r = flat >> 7, k = flat & 127;
      float4 v = make_float4(0.f, 0.f, 0.f, 0.f);
      if (r0 + r < n) v = *(const float4*)&((const float*)A)[(size_t)(r0 + r) * 128 + k];
      *(uint2*)&As[r][k] = cast4(v);
    }
  } else {
#pragma unroll
    for (int i = 0; i < 8; ++i) {
      int flat = (t + i * 256) * 8;
      int r = flat >> 7, k = flat & 127;
      uint4 v = make_uint4(0, 0, 0, 0);
      if (r0 + r < n) v = *(const uint4*)&((const ushort*)A)[(size_t)(r0 + r) * 128 + k];
      *(uint4*)&As[r][k] = v;
    }
  }
#pragma unroll
  for (int i = 0; i < 8; ++i) {
    int flat = (t + i * 256) * 8;
    int r = flat >> 7, k = flat & 127;
    *(uint4*)&Ws[r][k] = *(const uint4*)&W[flat];
  }
  __syncthreads();
  bf16x8 af[2][4];
#pragma unroll
  for (int rt = 0; rt < 2; ++rt)
#pragma unroll
    for (int ks = 0; ks < 4; ++ks)
      af[rt][ks] = *(const bf16x8*)&As[w * 32 + rt * 16 + m][ks * 32 + quad * 8];
#pragma unroll
  for (int ct = 0; ct < 8; ++ct) {
    bf16x8 bfr[4];
#pragma unroll
    for (int ks = 0; ks < 4; ++ks) bfr[ks] = *(const bf16x8*)&Ws[ct * 16 + m][ks * 32 + quad * 8];
    int c = ct * 16 + m;  // C/D: col = lane&15, row = quad*4 + reg
    float b = bias[c];
    float s1 = 0.f, s2 = 0.f;
#pragma unroll
    for (int rt = 0; rt < 2; ++rt) {
      f32x4 acc = {0.f, 0.f, 0.f, 0.f};
#pragma unroll
      for (int ks = 0; ks < 4; ++ks)
        acc = __builtin_amdgcn_mfma_f32_16x16x32_bf16(af[rt][ks], bfr[ks], acc, 0, 0, 0);
      int rbase = r0 + w * 32 + rt * 16 + quad * 4;
#pragma unroll
      for (int i2 = 0; i2 < 4; ++i2) {
        int r = rbase + i2;
        if (r < n) {
          float v = acc[i2] + b;
          s1 += v;
          s2 += v * v;
          Y[(size_t)r * 128 + c] = f2b(v);
        }
      }
    }
    s1 += __shfl_xor(s1, 16);
    s1 += __shfl_xor(s1, 32);
    s2 += __shfl_xor(s2, 16);
    s2 += __shfl_xor(s2, 32);
    if (quad == 0) {
      ls1[w][c] = s1;
      ls2[w][c] = s2;
    }
  }
  __syncthreads();
  if (t < 128) {
    float a1 = ls1[0][t] + ls1[1][t] + ls1[2][t] + ls1[3][t];
    float a2 = ls2[0][t] + ls2[1][t] + ls2[2][t] + ls2[3][t];
    atomicAdd(&sums[t], a1);
    atomicAdd(&sums[128 + t], a2);
  }
}

// ---------------- classifier MFMA: out[N,40](f32) = h(bf16) @ cls_w^T(bf16) + cls_b ----------------
__global__ __launch_bounds__(256) void k_mcls(const ushort* __restrict__ A,
                                              const ushort* __restrict__ W,
                                              const float* __restrict__ bias,
                                              float* __restrict__ out, int n) {
  __shared__ ushort As[64][136];
  __shared__ ushort Ws[48][136];  // rows 40..47 zero
  int t = threadIdx.x;
  int w = t >> 6, l = t & 63;
  int quad = l >> 4, m = l & 15;
  int r0 = blockIdx.x * 64;
#pragma unroll
  for (int i = 0; i < 4; ++i) {
    int flat = (t + i * 256) * 8;
    int r = flat >> 7, k = flat & 127;
    uint4 v = make_uint4(0, 0, 0, 0);
    if (r0 + r < n) v = *(const uint4*)&A[(size_t)(r0 + r) * 128 + k];
    *(uint4*)&As[r][k] = v;
  }
#pragma unroll
  for (int i = 0; i < 3; ++i) {
    int slot = t + i * 256;
    int flat = slot * 8;
    int r = flat >> 7, k = flat & 127;
    uint4 v = make_uint4(0, 0, 0, 0);
    if (r < 40) v = *(const uint4*)&W[flat];
    *(uint4*)&Ws[r][k] = v;
  }
  __syncthreads();
  bf16x8 af[4];
#pragma unroll
  for (int ks = 0; ks < 4; ++ks)
    af[ks] = *(const bf16x8*)&As[w * 16 + m][ks * 32 + quad * 8];
#pragma unroll
  for (int ct = 0; ct < 3; ++ct) {
    f32x4 acc = {0.f, 0.f, 0.f, 0.f};
#pragma unroll
    for (int ks = 0; ks < 4; ++ks) {
      bf16x8 bf = *(const bf16x8*)&Ws[ct * 16 + m][ks * 32 + quad * 8];
      acc = __builtin_amdgcn_mfma_f32_16x16x32_bf16(af[ks], bf, acc, 0, 0, 0);
    }
    int c = ct * 16 + m;
    if (c < DOUT) {
      float b = bias[c];
      int rbase = r0 + w * 16 + quad * 4;
#pragma unroll
      for (int i = 0; i < 4; ++i) {
        int r = rbase + i;
        if (r < n) out[(size_t)r * DOUT + c] = acc[i] + b;
      }
    }
  }
}

// ---------------- launch ----------------
extern "C" void kernel_launch(void* const* d_in, const int* in_sizes, int n_in,
                              void* d_out, int out_size, void* d_ws, size_t ws_size,
                              hipStream_t stream) {
  const float* x      = (const float*)d_in[0];
  const int*   ei     = (const int*)d_in[1];
  const float* fc_w   = (const float*)d_in[2];
  const float* fc_b   = (const float*)d_in[3];
  const float* conv_w = (const float*)d_in[4];
  const float* conv_b = (const float*)d_in[5];
  const float* bn_g   = (const float*)d_in[6];
  const float* bn_b   = (const float*)d_in[7];
  const float* cls_w  = (const float*)d_in[8];
  const float* cls_b  = (const float*)d_in[9];
  const int* row  = ei;       // edge_index[0]
  const int* colv = ei + EE;  // edge_index[1]

  char* w = (char*)d_ws;
  auto alloc = [&](size_t bytes) {
    char* p = w;
    w += (bytes + 255) & ~(size_t)255;
    return p;
  };
  ushort* hb     = (ushort*)alloc((size_t)NN * 128 * 2);
  ushort* x0b    = (ushort*)alloc((size_t)NN * 128 * 2);
  ushort* aggb   = (ushort*)alloc((size_t)NN * 128 * 2);
  ushort* yb     = (ushort*)alloc((size_t)NN * 128 * 2);
  ushort* wb_fc  = (ushort*)alloc(128 * 128 * 2);
  ushort* wb_cv  = (ushort*)alloc(3 * 128 * 128 * 2);
  ushort* wb_cls = (ushort*)alloc(DOUT * 128 * 2);
  int*   srcbuf  = (int*)alloc((size_t)EE * 4);
  uint*  pairbuf = (uint*)alloc((size_t)EE * 4);
  int*   hist_mat = (int*)alloc((size_t)NPB * NB * 4);
  int*   bbase   = (int*)alloc((NB + 1) * 4);
  int*   rowptr  = (int*)alloc((size_t)(NN + 1) * 4);
  float* dinv    = (float*)alloc((size_t)NN * 4);
  // contiguous zero region: sums(1024 floats) | gfill(196 ints)
  float* sums   = (float*)alloc(1024 * 4 + 196 * 4);
  int*   gfill  = (int*)(sums + 1024);

  // front: weight casts + zeros + per-block bucket histograms
  k_front<<<NFB + NPB, 256, 0, stream>>>(
      (const float4*)fc_w, (uint2*)wb_fc, (const float4*)conv_w, (uint2*)wb_cv,
      (const float4*)cls_w, (uint2*)wb_cls, (uint2*)sums, colv, hist_mat);
  k_bscan<<<1, 256, 0, stream>>>(hist_mat, bbase);
  k_part<<<NPB, 256, 0, stream>>>(row, colv, bbase, gfill, pairbuf);

  int gblocks = (NN + 127) / 128;

  // layer 0 GEMM (reads fp32 x directly), then fused place ∪ bnapply0
  k_mgemm<float><<<gblocks, 256, 0, stream>>>(x, wb_fc, fc_b, yb, sums + 0 * 256, NN);
  k_mid<<<NB + ABB, 256, 0, stream>>>(pairbuf, bbase, rowptr, dinv, srcbuf,
                                      (const uint2*)yb, (uint2*)hb, (uint2*)x0b,
                                      sums + 0 * 256, bn_g, bn_b);
  // conv layers
  for (int i = 0; i < 3; ++i) {
    k_spmm<<<(NN * 64 + 255) / 256, 256, 0, stream>>>((const uint4*)hb, (uint4*)aggb, rowptr, srcbuf, dinv);
    k_mgemm<ushort><<<gblocks, 256, 0, stream>>>(aggb, wb_cv + (size_t)i * 128 * 128, conv_b + (size_t)i * 128,
                                                 yb, sums + (size_t)(i + 1) * 256, NN);
    k_bnapply<<<ABB, 256, 0, stream>>>((const uint2*)yb, (uint2*)hb, (const uint2*)x0b,
                                       sums + (size_t)(i + 1) * 256,
                                       bn_g + (size_t)(i + 1) * 128, bn_b + (size_t)(i + 1) * 128);
  }
  // classifier
  k_mcls<<<(NN + 63) / 64, 256, 0, stream>>>(hb, wb_cls, cls_b, (float*)d_out, NN);
}

// Round 9
// 562.950 us; speedup vs baseline: 2.7601x; 1.0183x over previous
//
#include <hip/hip_runtime.h>
#include <hip/hip_bf16.h>

#define NN 100000
#define EE 1600000
#define DH 128
#define DOUT 40
#define BN_EPS 1e-5f

typedef unsigned int uint;
typedef unsigned short ushort;
typedef __attribute__((ext_vector_type(8))) short bf16x8;
typedef __attribute__((ext_vector_type(4))) float f32x4;

#define NB 196     // ceil(NN/512) buckets of 512 nodes
#define NPB 196    // partition/hist blocks: ceil(EE/PEB)
#define PEB 8192   // edges per partition block
#define ABB 2048   // bnapply grid-stride blocks
#define NFB 72     // k_front cast/zero blocks

__device__ __forceinline__ float b2f(uint u) { return __uint_as_float(u << 16); }
__device__ __forceinline__ ushort f2b(float f) {
  __hip_bfloat16 b = __float2bfloat16(f);
  return *reinterpret_cast<ushort*>(&b);
}
__device__ __forceinline__ uint2 cast4(float4 v) {
  uint2 o;
  o.x = (uint)f2b(v.x) | ((uint)f2b(v.y) << 16);
  o.y = (uint)f2b(v.z) | ((uint)f2b(v.w) << 16);
  return o;
}
// 8 fp32 -> bf16x8 fragment
__device__ __forceinline__ bf16x8 frag_f32(const float* p) {
  uint2 a = cast4(*(const float4*)p);
  uint2 b = cast4(*(const float4*)(p + 4));
  union { uint u[4]; bf16x8 v; } r;
  r.u[0] = a.x; r.u[1] = a.y; r.u[2] = b.x; r.u[3] = b.y;
  return r.v;
}

// ---------------- k_front: weight casts + zero region + bucket histograms ----------------
#define N4FC  4096      // 128*128/4
#define N4CV  12288     // 3*128*128/4
#define N4CLS 1280      // 40*128/4
#define NZ2   610       // (1024 sums + 196 gfill) / 2 uint2 zeros
__global__ __launch_bounds__(256) void k_front(const float4* __restrict__ w1s, uint2* __restrict__ w1d,
                                               const float4* __restrict__ w2s, uint2* __restrict__ w2d,
                                               const float4* __restrict__ w3s, uint2* __restrict__ w3d,
                                               uint2* __restrict__ zp,
                                               const int* __restrict__ col, int* __restrict__ hist_mat) {
  __shared__ int lh[NB];
  if (blockIdx.x < NFB) {
    int i = blockIdx.x * 256 + threadIdx.x;
    if (i < N4FC) { w1d[i] = cast4(w1s[i]); return; }
    i -= N4FC;
    if (i < N4CV) { w2d[i] = cast4(w2s[i]); return; }
    i -= N4CV;
    if (i < N4CLS) { w3d[i] = cast4(w3s[i]); return; }
    i -= N4CLS;
    if (i < NZ2) zp[i] = make_uint2(0, 0);
    return;
  }
  int hb = blockIdx.x - NFB;
  int tid = threadIdx.x;
  for (int i = tid; i < NB; i += 256) lh[i] = 0;
  __syncthreads();
  int base = hb * PEB;
#pragma unroll
  for (int i = 0; i < 32; ++i) {
    int e = base + i * 256 + tid;
    if (e < EE) atomicAdd(&lh[col[e] >> 9], 1);
  }
  __syncthreads();
  for (int i = tid; i < NB; i += 256) hist_mat[hb * NB + i] = lh[i];
}

// ---------------- k_bscan ----------------
__global__ void k_bscan(const int* __restrict__ hist_mat, int* __restrict__ bbase) {
  __shared__ int sm[256];
  int j = threadIdx.x;
  int tot = 0;
  if (j < NB)
    for (int i = 0; i < NPB; ++i) tot += hist_mat[i * NB + j];
  sm[j] = tot;
  __syncthreads();
  for (int off = 1; off < 256; off <<= 1) {
    int t = (j >= off) ? sm[j - off] : 0;
    __syncthreads();
    sm[j] += t;
    __syncthreads();
  }
  if (j < NB) bbase[j] = sm[j] - tot;
  if (j == NB - 1) bbase[NB] = sm[j];
}

// ---------------- k_part ----------------
__global__ __launch_bounds__(256) void k_part(const int* __restrict__ row, const int* __restrict__ col,
                                              const int* __restrict__ bbase, int* __restrict__ gfill,
                                              uint* __restrict__ pairbuf) {
  __shared__ int lhist[NB];
  __shared__ int lgoff[NB];
  __shared__ int lbase[NB];
  int tid = threadIdx.x;
  for (int i = tid; i < NB; i += 256) lhist[i] = 0;
  __syncthreads();
  int base = blockIdx.x * PEB;
  int packed[32];
#pragma unroll
  for (int i = 0; i < 32; ++i) {
    int e = base + i * 256 + tid;
    packed[i] = -1;
    if (e < EE) {
      int c = col[e];
      int b = c >> 9, loc = c & 511;
      int p = atomicAdd(&lhist[b], 1);
      packed[i] = (b << 22) | (loc << 13) | p;
    }
  }
  __syncthreads();
  for (int i = tid; i < NB; i += 256) {
    lgoff[i] = atomicAdd(&gfill[i], lhist[i]);
    lbase[i] = bbase[i];
  }
  __syncthreads();
#pragma unroll
  for (int i = 0; i < 32; ++i) {
    if (packed[i] >= 0) {
      int e = base + i * 256 + tid;
      int b = packed[i] >> 22, loc = (packed[i] >> 13) & 511, p = packed[i] & 8191;
      pairbuf[(size_t)lbase[b] + lgoff[b] + p] = ((uint)loc << 17) | (uint)row[e];
    }
  }
}

// ---------------- BN helpers ----------------
__device__ __forceinline__ void bn_prologue(float* ssl, const float* __restrict__ sums,
                                            const float* __restrict__ gamma,
                                            const float* __restrict__ beta) {
  int t = threadIdx.x;
  if (t < 128) {
    float mu = sums[t] * (1.f / NN);
    float var = sums[128 + t] * (1.f / NN) - mu * mu;
    float sc = gamma[t] * rsqrtf(var + BN_EPS);
    ssl[t] = sc;
    ssl[128 + t] = beta[t] - mu * sc;
  }
  __syncthreads();
}

__device__ __forceinline__ uint2 bn_elem(uint2 u, float4 sc, float4 sh) {
  float o0 = fmaxf(fmaf(sc.x, b2f(u.x & 0xffffu), sh.x), 0.f);
  float o1 = fmaxf(fmaf(sc.y, b2f(u.x >> 16), sh.y), 0.f);
  float o2 = fmaxf(fmaf(sc.z, b2f(u.y & 0xffffu), sh.z), 0.f);
  float o3 = fmaxf(fmaf(sc.w, b2f(u.y >> 16), sh.w), 0.f);
  uint2 o;
  o.x = (uint)f2b(o0) | ((uint)f2b(o1) << 16);
  o.y = (uint)f2b(o2) | ((uint)f2b(o3) << 16);
  return o;
}

__device__ __forceinline__ uint2 bn_elem_res(uint2 u, uint2 r, float4 sc, float4 sh) {
  float o0 = fmaxf(fmaf(sc.x, b2f(u.x & 0xffffu), sh.x), 0.f) + b2f(r.x & 0xffffu);
  float o1 = fmaxf(fmaf(sc.y, b2f(u.x >> 16), sh.y), 0.f) + b2f(r.x >> 16);
  float o2 = fmaxf(fmaf(sc.z, b2f(u.y & 0xffffu), sh.z), 0.f) + b2f(r.y & 0xffffu);
  float o3 = fmaxf(fmaf(sc.w, b2f(u.y >> 16), sh.w), 0.f) + b2f(r.y >> 16);
  uint2 o;
  o.x = (uint)f2b(o0) | ((uint)f2b(o1) << 16);
  o.y = (uint)f2b(o2) | ((uint)f2b(o3) << 16);
  return o;
}

// ---------------- k_mid: place ∪ bnapply layer-0 ----------------
__global__ __launch_bounds__(256) void k_mid(const uint* __restrict__ pairbuf,
                                             const int* __restrict__ bbase,
                                             int* __restrict__ rowptr, float* __restrict__ dinv,
                                             int* __restrict__ srcbuf,
                                             const uint2* __restrict__ y, uint2* __restrict__ h,
                                             uint2* __restrict__ x0, const float* __restrict__ sums,
                                             const float* __restrict__ gamma,
                                             const float* __restrict__ beta) {
  __shared__ __align__(16) int smraw[13569];  // stage[12288] | dega[512] | lrp[513] | ssum[256]
  if (blockIdx.x < NB) {
    int* stage = smraw;
    int* dega = smraw + 12288;
    int* lrp = smraw + 12800;
    int* ssum = smraw + 13313;
    int tid = threadIdx.x;
    int b = blockIdx.x;
    int nstart = b << 9;
    int nloc = min(nstart + 512, NN) - nstart;
    int estart = bbase[b];
    int count = bbase[b + 1] - estart;
    dega[tid] = 0;
    dega[256 + tid] = 0;
    __syncthreads();
    for (int i = tid; i < count; i += 256) atomicAdd(&dega[pairbuf[(size_t)estart + i] >> 17], 1);
    __syncthreads();
    int d0 = dega[2 * tid], d1 = dega[2 * tid + 1];
    ssum[tid] = d0 + d1;
    __syncthreads();
    for (int off = 1; off < 256; off <<= 1) {
      int t2 = (tid >= off) ? ssum[tid - off] : 0;
      __syncthreads();
      ssum[tid] += t2;
      __syncthreads();
    }
    int incl = ssum[tid];
    int ex = incl - (d0 + d1);
    lrp[2 * tid] = ex;
    lrp[2 * tid + 1] = ex + d0;
    if (tid == 255) lrp[512] = incl;
    __syncthreads();
    for (int i = tid; i < nloc; i += 256) {
      rowptr[nstart + i] = estart + lrp[i];
      int dg = dega[i];
      dinv[nstart + i] = (dg > 0) ? rsqrtf((float)dg) : 0.f;
    }
    if (b == NB - 1 && tid == 0) rowptr[NN] = estart + count;
    __syncthreads();
    dega[tid] = 0;
    dega[256 + tid] = 0;
    __syncthreads();
    if (count <= 12288) {
      for (int i = tid; i < count; i += 256) {
        uint v = pairbuf[(size_t)estart + i];
        int loc = v >> 17;
        int p = atomicAdd(&dega[loc], 1);
        stage[lrp[loc] + p] = (int)(v & 0x1FFFFu);
      }
      __syncthreads();
      for (int i = tid; i < count; i += 256) srcbuf[estart + i] = stage[i];
    } else {
      for (int i = tid; i < count; i += 256) {
        uint v = pairbuf[(size_t)estart + i];
        int loc = v >> 17;
        int p = atomicAdd(&dega[loc], 1);
        srcbuf[estart + lrp[loc] + p] = (int)(v & 0x1FFFFu);
      }
    }
    return;
  }
  float* ssl = (float*)smraw;
  bn_prologue(ssl, sums, gamma, beta);
  const float4* ss4 = (const float4*)ssl;
  for (int i = (blockIdx.x - NB) * 256 + threadIdx.x; i < NN * 32; i += ABB * 256) {
    int j = i & 31;
    uint2 o = bn_elem(y[i], ss4[j], ss4[32 + j]);
    h[i] = o;
    x0[i] = o;
  }
}

// ---------------- bnapply (layers 1..3) ----------------
__global__ __launch_bounds__(256) void k_bnapply(const uint2* __restrict__ y, uint2* __restrict__ h,
                                                 const uint2* __restrict__ res,
                                                 const float* __restrict__ sums,
                                                 const float* __restrict__ gamma,
                                                 const float* __restrict__ beta) {
  __shared__ __align__(16) float ssl[256];
  bn_prologue(ssl, sums, gamma, beta);
  const float4* ss4 = (const float4*)ssl;
  for (int i = blockIdx.x * 256 + threadIdx.x; i < NN * 32; i += ABB * 256) {
    int j = i & 31;
    h[i] = bn_elem_res(y[i], res[i], ss4[j], ss4[32 + j]);
  }
}

// ---------------- SPMM (unchanged from r8) ----------------
__device__ __forceinline__ void fmac8(float* acc, uint4 v, float wgt) {
  acc[0] = fmaf(wgt, b2f(v.x & 0xffffu), acc[0]);
  acc[1] = fmaf(wgt, b2f(v.x >> 16), acc[1]);
  acc[2] = fmaf(wgt, b2f(v.y & 0xffffu), acc[2]);
  acc[3] = fmaf(wgt, b2f(v.y >> 16), acc[3]);
  acc[4] = fmaf(wgt, b2f(v.z & 0xffffu), acc[4]);
  acc[5] = fmaf(wgt, b2f(v.z >> 16), acc[5]);
  acc[6] = fmaf(wgt, b2f(v.w & 0xffffu), acc[6]);
  acc[7] = fmaf(wgt, b2f(v.w >> 16), acc[7]);
}

__global__ __launch_bounds__(256) void k_spmm(const uint4* __restrict__ h4, uint4* __restrict__ agg4,
                                              const int* __restrict__ rowptr,
                                              const int* __restrict__ srcbuf,
                                              const float* __restrict__ dinv) {
  int gid = blockIdx.x * 256 + threadIdx.x;
  int node = gid >> 6;
  if (node >= NN) return;
  int lane = threadIdx.x & 63;
  int g = lane >> 4, li = lane & 15;
  int e0 = rowptr[node], e1 = rowptr[node + 1];
  float acc[8];
#pragma unroll
  for (int j = 0; j < 8; ++j) acc[j] = 0.f;

  int eA = e0 + g;
  int s0 = (eA < e1) ? srcbuf[eA] : -1;
  int s1 = (eA + 4 < e1) ? srcbuf[eA + 4] : -1;
  int s2 = (eA + 8 < e1) ? srcbuf[eA + 8] : -1;
  int s3 = (eA + 12 < e1) ? srcbuf[eA + 12] : -1;
  while (eA < e1) {
    int eN = eA + 16;
    int t0 = (eN < e1) ? srcbuf[eN] : -1;
    int t1 = (eN + 4 < e1) ? srcbuf[eN + 4] : -1;
    int t2 = (eN + 8 < e1) ? srcbuf[eN + 8] : -1;
    int t3 = (eN + 12 < e1) ? srcbuf[eN + 12] : -1;
    int a1 = (s1 >= 0) ? s1 : s0;
    int a2 = (s2 >= 0) ? s2 : s0;
    int a3 = (s3 >= 0) ? s3 : s0;
    float w0 = dinv[s0];
    uint4 v0 = h4[(size_t)s0 * 16 + li];
    float w1 = (s1 >= 0) ? dinv[a1] : 0.f;
    uint4 v1 = h4[(size_t)a1 * 16 + li];
    float w2 = (s2 >= 0) ? dinv[a2] : 0.f;
    uint4 v2 = h4[(size_t)a2 * 16 + li];
    float w3 = (s3 >= 0) ? dinv[a3] : 0.f;
    uint4 v3 = h4[(size_t)a3 * 16 + li];
    fmac8(acc, v0, w0);
    fmac8(acc, v1, w1);
    fmac8(acc, v2, w2);
    fmac8(acc, v3, w3);
    s0 = t0; s1 = t1; s2 = t2; s3 = t3;
    eA = eN;
  }
#pragma unroll
  for (int j = 0; j < 8; ++j) {
    acc[j] += __shfl_xor(acc[j], 16);
    acc[j] += __shfl_xor(acc[j], 32);
  }
  if (g == 0) {
    float dc = dinv[node];
    uint4 o;
    o.x = (uint)f2b(acc[0] * dc) | ((uint)f2b(acc[1] * dc) << 16);
    o.y = (uint)f2b(acc[2] * dc) | ((uint)f2b(acc[3] * dc) << 16);
    o.z = (uint)f2b(acc[4] * dc) | ((uint)f2b(acc[5] * dc) << 16);
    o.w = (uint)f2b(acc[6] * dc) | ((uint)f2b(acc[7] * dc) << 16);
    agg4[(size_t)node * 16 + li] = o;
  }
}

// ---------------- MFMA GEMM, direct-fragment (no LDS staging): Y = A @ W^T + b, + BN stats ----------------
// Fragments are 8 contiguous k-elements -> 16B global loads. W is L2-resident (32KB).
template <typename TA>
__global__ __launch_bounds__(256) void k_mgemm(const TA* __restrict__ A,
                                               const ushort* __restrict__ W,
                                               const float* __restrict__ bias,
                                               ushort* __restrict__ Y,
                                               float* __restrict__ sums, int n) {
  __shared__ float ls1[4][128];
  __shared__ float ls2[4][128];
  int t = threadIdx.x;
  int w = t >> 6, l = t & 63;
  int quad = l >> 4, m = l & 15;
  int r0 = blockIdx.x * 128;
  // A fragments: rows r0 + w*32 + rt*16 + m, k = ks*32 + quad*8 (clamped rows never stored)
  bf16x8 af[2][4];
#pragma unroll
  for (int rt = 0; rt < 2; ++rt) {
    int ar = min(r0 + w * 32 + rt * 16 + m, n - 1);
#pragma unroll
    for (int ks = 0; ks < 4; ++ks) {
      if constexpr (sizeof(TA) == 4)
        af[rt][ks] = frag_f32((const float*)A + (size_t)ar * 128 + ks * 32 + quad * 8);
      else
        af[rt][ks] = *(const bf16x8*)((const ushort*)A + (size_t)ar * 128 + ks * 32 + quad * 8);
    }
  }
#pragma unroll
  for (int ct = 0; ct < 8; ++ct) {
    int c = ct * 16 + m;  // C/D: col = lane&15, row = quad*4 + reg
    bf16x8 bfr[4];
#pragma unroll
    for (int ks = 0; ks < 4; ++ks)
      bfr[ks] = *(const bf16x8*)&W[(size_t)c * 128 + ks * 32 + quad * 8];
    float b = bias[c];
    float s1 = 0.f, s2 = 0.f;
#pragma unroll
    for (int rt = 0; rt < 2; ++rt) {
      f32x4 acc = {0.f, 0.f, 0.f, 0.f};
#pragma unroll
      for (int ks = 0; ks < 4; ++ks)
        acc = __builtin_amdgcn_mfma_f32_16x16x32_bf16(af[rt][ks], bfr[ks], acc, 0, 0, 0);
      int rbase = r0 + w * 32 + rt * 16 + quad * 4;
#pragma unroll
      for (int i2 = 0; i2 < 4; ++i2) {
        int r = rbase + i2;
        if (r < n) {
          float v = acc[i2] + b;
          s1 += v;
          s2 += v * v;
          Y[(size_t)r * 128 + c] = f2b(v);
        }
      }
    }
    s1 += __shfl_xor(s1, 16);
    s1 += __shfl_xor(s1, 32);
    s2 += __shfl_xor(s2, 16);
    s2 += __shfl_xor(s2, 32);
    if (quad == 0) {
      ls1[w][c] = s1;
      ls2[w][c] = s2;
    }
  }
  __syncthreads();
  if (t < 128) {
    float a1 = ls1[0][t] + ls1[1][t] + ls1[2][t] + ls1[3][t];
    float a2 = ls2[0][t] + ls2[1][t] + ls2[2][t] + ls2[3][t];
    atomicAdd(&sums[t], a1);
    atomicAdd(&sums[128 + t], a2);
  }
}

// ---------------- classifier MFMA, direct-fragment: out[N,40](f32) = h @ cls_w^T + cls_b ----------------
__global__ __launch_bounds__(256) void k_mcls(const ushort* __restrict__ A,
                                              const ushort* __restrict__ W,
                                              const float* __restrict__ bias,
                                              float* __restrict__ out, int n) {
  int t = threadIdx.x;
  int w = t >> 6, l = t & 63;
  int quad = l >> 4, m = l & 15;
  int r0 = blockIdx.x * 64;
  int ar = min(r0 + w * 16 + m, n - 1);
  bf16x8 af[4];
#pragma unroll
  for (int ks = 0; ks < 4; ++ks)
    af[ks] = *(const bf16x8*)&A[(size_t)ar * 128 + ks * 32 + quad * 8];
#pragma unroll
  for (int ct = 0; ct < 3; ++ct) {
    int c = ct * 16 + m;
    int wr = min(c, DOUT - 1);  // garbage cols >= 40 stay in unwritten lanes
    bf16x8 bfr[4];
#pragma unroll
    for (int ks = 0; ks < 4; ++ks)
      bfr[ks] = *(const bf16x8*)&W[(size_t)wr * 128 + ks * 32 + quad * 8];
    f32x4 acc = {0.f, 0.f, 0.f, 0.f};
#pragma unroll
    for (int ks = 0; ks < 4; ++ks)
      acc = __builtin_amdgcn_mfma_f32_16x16x32_bf16(af[ks], bfr[ks], acc, 0, 0, 0);
    if (c < DOUT) {
      float b = bias[c];
      int rbase = r0 + w * 16 + quad * 4;
#pragma unroll
      for (int i = 0; i < 4; ++i) {
        int r = rbase + i;
        if (r < n) out[(size_t)r * DOUT + c] = acc[i] + b;
      }
    }
  }
}

// ---------------- launch ----------------
extern "C" void kernel_launch(void* const* d_in, const int* in_sizes, int n_in,
                              void* d_out, int out_size, void* d_ws, size_t ws_size,
                              hipStream_t stream) {
  const float* x      = (const float*)d_in[0];
  const int*   ei     = (const int*)d_in[1];
  const float* fc_w   = (const float*)d_in[2];
  const float* fc_b   = (const float*)d_in[3];
  const float* conv_w = (const float*)d_in[4];
  const float* conv_b = (const float*)d_in[5];
  const float* bn_g   = (const float*)d_in[6];
  const float* bn_b   = (const float*)d_in[7];
  const float* cls_w  = (const float*)d_in[8];
  const float* cls_b  = (const float*)d_in[9];
  const int* row  = ei;       // edge_index[0]
  const int* colv = ei + EE;  // edge_index[1]

  char* w = (char*)d_ws;
  auto alloc = [&](size_t bytes) {
    char* p = w;
    w += (bytes + 255) & ~(size_t)255;
    return p;
  };
  ushort* hb     = (ushort*)alloc((size_t)NN * 128 * 2);
  ushort* x0b    = (ushort*)alloc((size_t)NN * 128 * 2);
  ushort* aggb   = (ushort*)alloc((size_t)NN * 128 * 2);
  ushort* yb     = (ushort*)alloc((size_t)NN * 128 * 2);
  ushort* wb_fc  = (ushort*)alloc(128 * 128 * 2);
  ushort* wb_cv  = (ushort*)alloc(3 * 128 * 128 * 2);
  ushort* wb_cls = (ushort*)alloc(DOUT * 128 * 2);
  int*   srcbuf  = (int*)alloc((size_t)EE * 4);
  uint*  pairbuf = (uint*)alloc((size_t)EE * 4);
  int*   hist_mat = (int*)alloc((size_t)NPB * NB * 4);
  int*   bbase   = (int*)alloc((NB + 1) * 4);
  int*   rowptr  = (int*)alloc((size_t)(NN + 1) * 4);
  float* dinv    = (float*)alloc((size_t)NN * 4);
  // contiguous zero region: sums(1024 floats) | gfill(196 ints)
  float* sums   = (float*)alloc(1024 * 4 + 196 * 4);
  int*   gfill  = (int*)(sums + 1024);

  // front: weight casts + zeros + per-block bucket histograms
  k_front<<<NFB + NPB, 256, 0, stream>>>(
      (const float4*)fc_w, (uint2*)wb_fc, (const float4*)conv_w, (uint2*)wb_cv,
      (const float4*)cls_w, (uint2*)wb_cls, (uint2*)sums, colv, hist_mat);
  k_bscan<<<1, 256, 0, stream>>>(hist_mat, bbase);
  k_part<<<NPB, 256, 0, stream>>>(row, colv, bbase, gfill, pairbuf);

  int gblocks = (NN + 127) / 128;

  // layer 0 GEMM (reads fp32 x directly), then fused place ∪ bnapply0
  k_mgemm<float><<<gblocks, 256, 0, stream>>>(x, wb_fc, fc_b, yb, sums + 0 * 256, NN);
  k_mid<<<NB + ABB, 256, 0, stream>>>(pairbuf, bbase, rowptr, dinv, srcbuf,
                                      (const uint2*)yb, (uint2*)hb, (uint2*)x0b,
                                      sums + 0 * 256, bn_g, bn_b);
  // conv layers
  for (int i = 0; i < 3; ++i) {
    k_spmm<<<(NN * 64 + 255) / 256, 256, 0, stream>>>((const uint4*)hb, (uint4*)aggb, rowptr, srcbuf, dinv);
    k_mgemm<ushort><<<gblocks, 256, 0, stream>>>(aggb, wb_cv + (size_t)i * 128 * 128, conv_b + (size_t)i * 128,
                                                 yb, sums + (size_t)(i + 1) * 256, NN);
    k_bnapply<<<ABB, 256, 0, stream>>>((const uint2*)yb, (uint2*)hb, (const uint2*)x0b,
                                       sums + (size_t)(i + 1) * 256,
                                       bn_g + (size_t)(i + 1) * 128, bn_b + (size_t)(i + 1) * 128);
  }
  // classifier
  k_mcls<<<(NN + 63) / 64, 256, 0, stream>>>(hb, wb_cls, cls_b, (float*)d_out, NN);
}